// Round 1
// baseline (1430.078 us; speedup 1.0000x reference)
//
#include <hip/hip_runtime.h>

#define B_  4
#define C_  256
#define H_  64
#define HW_ 4096

// -------------------- weight transposes --------------------
// wT[br][ci][n][co], flat idx = ((br*256+ci)*9+n)*256+co
__global__ void k_transpose_w(const float* __restrict__ wx,
                              const float* __restrict__ wy,
                              float* __restrict__ wT) {
    int idx = blockIdx.x * 256 + threadIdx.x;          // < 1179648
    int br  = idx / 589824;
    int rem = idx % 589824;
    int co  = rem % 256;
    int t   = rem / 256;                               // ci*9+n
    int n   = t % 9, ci = t / 9;
    const float* w = br ? wy : wx;
    wT[idx] = w[(co * 256 + ci) * 9 + n];
}

// pwT[ci][n][ch36], ch36: 0..17 branch x, 18..35 branch y
__global__ void k_transpose_pw(const float* __restrict__ pwx,
                               const float* __restrict__ pwy,
                               float* __restrict__ pwT) {
    int idx  = blockIdx.x * 256 + threadIdx.x;         // < 82944
    int ch36 = idx % 36;
    int t    = idx / 36;
    int n    = t % 9, ci = t / 9;
    int br   = ch36 / 18, ch = ch36 % 18;
    const float* pw = br ? pwy : pwx;
    pwT[idx] = pw[(ch * 256 + ci) * 9 + n];
}

// -------------------- offset conv (both branches fused) --------------------
// off[br][b][ch18][h][w]
__global__ __launch_bounds__(256) void k_offset(const float* __restrict__ x,
                                                const float* __restrict__ pwT,
                                                const float* __restrict__ pbx,
                                                const float* __restrict__ pby,
                                                float* __restrict__ off) {
    __shared__ float rows[198];   // [3][66] rows h-1..h+1, col-padded
    __shared__ float pwl[324];    // [9][36]
    int h = blockIdx.x, b = blockIdx.y;
    int t = threadIdx.x;
    int w0  = t & 63;
    int g   = t >> 6;             // wave id 0..3
    int chb = g * 9;              // 9 channels of 36 per wave

    float acc[9];
#pragma unroll
    for (int i = 0; i < 9; ++i) acc[i] = 0.f;

    for (int ci = 0; ci < 256; ++ci) {
        __syncthreads();
        if (t < 198) {
            int r = t / 66, c = t % 66;
            int gr = h - 1 + r, gc = c - 1;
            float v = 0.f;
            if ((unsigned)gr < 64u && (unsigned)gc < 64u)
                v = x[((b * 256 + ci) * 64 + gr) * 64 + gc];
            rows[t] = v;
        }
        if (t < 81)
            ((float4*)pwl)[t] = ((const float4*)pwT)[ci * 81 + t];
        __syncthreads();
#pragma unroll
        for (int k9 = 0; k9 < 9; ++k9) {
            int ki = k9 / 3, kj = k9 % 3;
            float xv = rows[ki * 66 + w0 + kj];
#pragma unroll
            for (int c9 = 0; c9 < 9; ++c9)
                acc[c9] += pwl[k9 * 36 + chb + c9] * xv;
        }
    }
#pragma unroll
    for (int c9 = 0; c9 < 9; ++c9) {
        int ch36 = chb + c9;
        int br = ch36 / 18, ch = ch36 % 18;
        float bias = br ? pby[ch] : pbx[ch];
        off[((br * 4 + b) * 18 + ch) * 4096 + h * 64 + w0] = acc[c9] + bias;
    }
}

// -------------------- bilinear sampling params --------------------
// pg[idx] = (g_lt, g_rb, g_lb, g_rt); pi[idx] = ltx|lty<<8|rbx<<16|rby<<24
// idx = ((br*4+b)*9+n)*4096 + pix
__global__ void k_params(const float* __restrict__ off,
                         float4* __restrict__ pg,
                         unsigned* __restrict__ pi) {
    int idx = blockIdx.x * 256 + threadIdx.x;          // < 294912
    int pix = idx & 4095;
    int n   = (idx >> 12) % 9;
    int b   = (idx / 36864) & 3;
    int br  = idx / 147456;
    int h = pix >> 6, w = pix & 63;
    int i = n / 3, j = n % 3;

    float offx = off[((br * 4 + b) * 18 + n) * 4096 + pix];
    float offy = off[((br * 4 + b) * 18 + n + 9) * 4096 + pix];
    float px = offx + (float)(i - 1) + (float)(h + 1);
    float py = offy + (float)(j - 1) + (float)(w + 1);
    float fx = floorf(px), fy = floorf(py);
    int ltx = min(max((int)fx, 0), 65);
    int lty = min(max((int)fy, 0), 65);
    int rbx = min(max((int)fx + 1, 0), 65);
    int rby = min(max((int)fy + 1, 0), 65);
    float pxc = fminf(fmaxf(px, 0.f), 65.f);
    float pyc = fminf(fmaxf(py, 0.f), 65.f);
    float ax_lt = 1.f + ((float)ltx - pxc);
    float ax_rb = 1.f - ((float)rbx - pxc);
    float ay_lt = 1.f + ((float)lty - pyc);
    float ay_rb = 1.f - ((float)rby - pyc);
    pg[idx] = make_float4(ax_lt * ay_lt, ax_rb * ay_rb, ax_lt * ay_rb, ax_rb * ay_lt);
    pi[idx] = (unsigned)ltx | ((unsigned)lty << 8) | ((unsigned)rbx << 16) | ((unsigned)rby << 24);
}

// -------------------- main deformable conv: fused implicit GEMM --------------------
// block: all 256 co x 64-pixel row tile. grid (64 rows, 4 b, 2 branches)
__global__ __launch_bounds__(256, 2) void k_deform(const float* __restrict__ x,
                                                   const float* __restrict__ wT,
                                                   const float4* __restrict__ pg,
                                                   const unsigned* __restrict__ pi,
                                                   float* __restrict__ Cx,
                                                   float* __restrict__ Cy) {
    __shared__ float img[4096];    // x[b][ci] 64x64 (pad handled at gather)
    __shared__ float samp[576];    // [n9][pix64]
    __shared__ float wl[2304];     // [n9][co256]
    int h = blockIdx.x, b = blockIdx.y, br = blockIdx.z;
    int t = threadIdx.x;
    int cob = (t >> 3) << 3;       // co base, 32 groups of 8
    int pxb = (t & 7) << 3;        // pix base, 8 groups of 8
    bool sampler = t < 192;

    float4 g4[3];
    unsigned pk[3];
    if (sampler) {
#pragma unroll
        for (int q = 0; q < 3; ++q) {
            int s = t * 3 + q;
            int n = s >> 6, pw = s & 63;
            int pidx = ((br * 4 + b) * 9 + n) * 4096 + h * 64 + pw;
            g4[q] = pg[pidx];
            pk[q] = pi[pidx];
        }
    }

    float acc[8][8];
#pragma unroll
    for (int i = 0; i < 8; ++i)
#pragma unroll
        for (int j = 0; j < 8; ++j) acc[i][j] = 0.f;

    const float4* x4 = (const float4*)x;
    for (int ci = 0; ci < 256; ++ci) {
        // stage channel image
        int base4 = (b * 256 + ci) * 1024;
#pragma unroll
        for (int k = 0; k < 4; ++k)
            ((float4*)img)[k * 256 + t] = x4[base4 + k * 256 + t];
        __syncthreads();
        // stage weights [n][co] + compute samples
#pragma unroll
        for (int k = 0; k < 9; ++k)
            wl[k * 256 + t] = wT[((br * 256 + ci) * 9 + k) * 256 + t];
        if (sampler) {
#pragma unroll
            for (int q = 0; q < 3; ++q) {
                unsigned p = pk[q];
                int ltx = p & 255, lty = (p >> 8) & 255;
                int rbx = (p >> 16) & 255, rby = (p >> 24) & 255;
                unsigned a0 = (unsigned)(ltx - 1), b0 = (unsigned)(lty - 1);
                unsigned a1 = (unsigned)(rbx - 1), b1 = (unsigned)(rby - 1);
                float v_lt = (a0 < 64u && b0 < 64u) ? img[a0 * 64 + b0] : 0.f;
                float v_rb = (a1 < 64u && b1 < 64u) ? img[a1 * 64 + b1] : 0.f;
                float v_lb = (a0 < 64u && b1 < 64u) ? img[a0 * 64 + b1] : 0.f;
                float v_rt = (a1 < 64u && b0 < 64u) ? img[a1 * 64 + b0] : 0.f;
                samp[t * 3 + q] = g4[q].x * v_lt + g4[q].y * v_rb
                                + g4[q].z * v_lb + g4[q].w * v_rt;
            }
        }
        __syncthreads();
        // 8x8 FMA tile over 9 kernel taps
#pragma unroll
        for (int k = 0; k < 9; ++k) {
            const float* wp = wl + k * 256 + cob;
            const float* sp = samp + k * 64 + pxb;
            float4 wa = *(const float4*)wp;
            float4 wb = *(const float4*)(wp + 4);
            float4 sa = *(const float4*)sp;
            float4 sb = *(const float4*)(sp + 4);
            float wv[8] = {wa.x, wa.y, wa.z, wa.w, wb.x, wb.y, wb.z, wb.w};
            float sv[8] = {sa.x, sa.y, sa.z, sa.w, sb.x, sb.y, sb.z, sb.w};
#pragma unroll
            for (int ii = 0; ii < 8; ++ii)
#pragma unroll
                for (int jj = 0; jj < 8; ++jj)
                    acc[ii][jj] += wv[ii] * sv[jj];
        }
    }

    float* Cd = br ? Cy : Cx;
#pragma unroll
    for (int ii = 0; ii < 8; ++ii) {
        float* rp = Cd + ((b * 256 + cob + ii) * 4096) + h * 64 + pxb;
        *(float4*)rp       = make_float4(acc[ii][0], acc[ii][1], acc[ii][2], acc[ii][3]);
        *(float4*)(rp + 4) = make_float4(acc[ii][4], acc[ii][5], acc[ii][6], acc[ii][7]);
    }
}

// -------------------- 1x1 conv + bias + residual --------------------
// grid (64 pixtiles, 4 b, 4 co-tiles), block 256, 4x4 per thread
__global__ __launch_bounds__(256) void k_final(const float* __restrict__ Cx,
                                               const float* __restrict__ Cy,
                                               const float* __restrict__ wo,
                                               const float* __restrict__ bo,
                                               const float* __restrict__ x,
                                               float* __restrict__ out) {
    __shared__ float A[2048];   // [k32][co64]
    __shared__ float Bs[2048];  // [k32][p64]
    int pt = blockIdx.x, b = blockIdx.y, cot = blockIdx.z;
    int t = threadIdx.x;
    int pixbase = pt * 64;

    float acc[4][4];
#pragma unroll
    for (int i = 0; i < 4; ++i)
#pragma unroll
        for (int j = 0; j < 4; ++j) acc[i][j] = 0.f;

    int col = t / 4, kk0 = (t % 4) * 8;   // A staging coords
    int bk = t / 8, bp = (t % 8) * 8;     // B staging coords

    for (int kc = 0; kc < 512; kc += 32) {
        __syncthreads();
        {   // stage A: w_o[cot*64+col][kc+kk0 .. +8] -> A[kk][col]
            const float* ap = wo + (cot * 64 + col) * 512 + kc + kk0;
            float4 a0 = *(const float4*)ap;
            float4 a1 = *(const float4*)(ap + 4);
            A[(kk0 + 0) * 64 + col] = a0.x;
            A[(kk0 + 1) * 64 + col] = a0.y;
            A[(kk0 + 2) * 64 + col] = a0.z;
            A[(kk0 + 3) * 64 + col] = a0.w;
            A[(kk0 + 4) * 64 + col] = a1.x;
            A[(kk0 + 5) * 64 + col] = a1.y;
            A[(kk0 + 6) * 64 + col] = a1.z;
            A[(kk0 + 7) * 64 + col] = a1.w;
        }
        {   // stage B: cat[b][kc+bk][pixbase+bp .. +8]
            int kg = kc + bk;
            const float* src = (kg < 256) ? Cx : Cy;
            int ch = kg & 255;
            const float* sp = src + ((b * 256 + ch) * 4096) + pixbase + bp;
            *(float4*)(Bs + bk * 64 + bp)     = *(const float4*)sp;
            *(float4*)(Bs + bk * 64 + bp + 4) = *(const float4*)(sp + 4);
        }
        __syncthreads();
#pragma unroll
        for (int k = 0; k < 32; ++k) {
            float4 av = *(const float4*)(A + k * 64 + (t >> 4) * 4);
            float4 bv = *(const float4*)(Bs + k * 64 + (t & 15) * 4);
            float a4[4] = {av.x, av.y, av.z, av.w};
            float b4[4] = {bv.x, bv.y, bv.z, bv.w};
#pragma unroll
            for (int ii = 0; ii < 4; ++ii)
#pragma unroll
                for (int jj = 0; jj < 4; ++jj)
                    acc[ii][jj] += a4[ii] * b4[jj];
        }
    }

    int coq = cot * 64 + (t >> 4) * 4;
    int pq  = pixbase + (t & 15) * 4;
#pragma unroll
    for (int ii = 0; ii < 4; ++ii) {
        int co = coq + ii;
        const float4 xr = *(const float4*)(x + (b * 256 + co) * 4096 + pq);
        float bias = bo[co];
        float4 o;
        o.x = acc[ii][0] + bias + xr.x;
        o.y = acc[ii][1] + bias + xr.y;
        o.z = acc[ii][2] + bias + xr.z;
        o.w = acc[ii][3] + bias + xr.w;
        *(float4*)(out + (b * 256 + co) * 4096 + pq) = o;
    }
}

// -------------------- launch --------------------
extern "C" void kernel_launch(void* const* d_in, const int* in_sizes, int n_in,
                              void* d_out, int out_size, void* d_ws, size_t ws_size,
                              hipStream_t stream) {
    const float* x   = (const float*)d_in[0];
    const float* pwx = (const float*)d_in[1];
    const float* pbx = (const float*)d_in[2];
    const float* wx  = (const float*)d_in[3];
    const float* pwy = (const float*)d_in[4];
    const float* pby = (const float*)d_in[5];
    const float* wy  = (const float*)d_in[6];
    const float* wo  = (const float*)d_in[7];
    const float* bo  = (const float*)d_in[8];
    float* out = (float*)d_out;

    char* ws = (char*)d_ws;
    float*    off = (float*)ws;                       // 589824 f  = 2359296 B
    float4*   pg  = (float4*)(ws + 2359296);          // 294912 f4 = 4718592 B
    unsigned* pi  = (unsigned*)(ws + 7077888);        // 294912 u32= 1179648 B
    float*    wT  = (float*)(ws + 8257536);           // 1179648 f = 4718592 B
    float*    pwT = (float*)(ws + 12976128);          // 82944 f   = 331776 B
    float*    Cx  = (float*)(ws + 13307904);          // 4194304 f
    float*    Cy  = (float*)(ws + 30085120);          // 4194304 f

    k_transpose_w <<<4608, 256, 0, stream>>>(wx, wy, wT);
    k_transpose_pw<<<324,  256, 0, stream>>>(pwx, pwy, pwT);
    k_offset      <<<dim3(64, 4),    256, 0, stream>>>(x, pwT, pbx, pby, off);
    k_params      <<<1152, 256, 0, stream>>>(off, pg, pi);
    k_deform      <<<dim3(64, 4, 2), 256, 0, stream>>>(x, wT, pg, pi, Cx, Cy);
    k_final       <<<dim3(64, 4, 4), 256, 0, stream>>>(Cx, Cy, wo, bo, x, out);
}

// Round 2
// 1101.183 us; speedup vs baseline: 1.2987x; 1.2987x over previous
//
#include <hip/hip_runtime.h>

typedef unsigned short u16;
typedef __attribute__((ext_vector_type(8))) short bf16x8;
typedef __attribute__((ext_vector_type(4))) float f32x4;
typedef __attribute__((ext_vector_type(4))) u16 u16x4;

__device__ __forceinline__ unsigned f2bf(float f) {
    unsigned u = __float_as_uint(f);
    return (u + 0x7FFFu + ((u >> 16) & 1u)) >> 16;   // RNE, finite inputs
}

__device__ __forceinline__ void gll16(const void* g, void* l) {
    __builtin_amdgcn_global_load_lds(
        (const __attribute__((address_space(1))) char*)g,
        (__attribute__((address_space(3))) char*)l, 16, 0, 0);
}

// ---------- weight → panel transposes ----------
// Apan[br][kt72][co256][kw32], k = kt*32+kw = n9*256+ci
__global__ void k_transpose_w(const float* __restrict__ wx,
                              const float* __restrict__ wy,
                              u16* __restrict__ Apan) {
    int idx = blockIdx.x * 256 + threadIdx.x;          // < 1179648
    int br = idx / 589824, rem = idx % 589824;
    int kt = rem / 8192, r2 = rem % 8192;
    int co = r2 / 32, kw = r2 % 32;
    int k = kt * 32 + kw, n9 = k >> 8, ci = k & 255;
    const float* w = br ? wy : wx;
    Apan[idx] = (u16)f2bf(w[(co * 256 + ci) * 9 + n9]);
}

// Af[kt16][co256][kw32], k = ch in concat(Cx,Cy)
__global__ void k_transpose_wo(const float* __restrict__ wo, u16* __restrict__ Af) {
    int idx = blockIdx.x * 256 + threadIdx.x;          // < 131072
    int kt = idx / 8192, r2 = idx % 8192;
    int co = r2 / 32, kw = r2 % 32;
    Af[idx] = (u16)f2bf(wo[co * 512 + kt * 32 + kw]);
}

// pwT[ci][n][ch36] (fp32, for k_offset)
__global__ void k_transpose_pw(const float* __restrict__ pwx,
                               const float* __restrict__ pwy,
                               float* __restrict__ pwT) {
    int idx  = blockIdx.x * 256 + threadIdx.x;         // < 82944
    int ch36 = idx % 36;
    int t    = idx / 36;
    int n    = t % 9, ci = t / 9;
    int br   = ch36 / 18, ch = ch36 % 18;
    const float* pw = br ? pwy : pwx;
    pwT[idx] = pw[(ch * 256 + ci) * 9 + n];
}

// ---------- offset conv (fp32, both branches) ----------
__global__ __launch_bounds__(256) void k_offset(const float* __restrict__ x,
                                                const float* __restrict__ pwT,
                                                const float* __restrict__ pbx,
                                                const float* __restrict__ pby,
                                                float* __restrict__ off) {
    __shared__ float rows[198];
    __shared__ float pwl[324];
    int h = blockIdx.x, b = blockIdx.y;
    int t = threadIdx.x;
    int w0  = t & 63;
    int g   = t >> 6;
    int chb = g * 9;

    float acc[9];
#pragma unroll
    for (int i = 0; i < 9; ++i) acc[i] = 0.f;

    for (int ci = 0; ci < 256; ++ci) {
        __syncthreads();
        if (t < 198) {
            int r = t / 66, c = t % 66;
            int gr = h - 1 + r, gc = c - 1;
            float v = 0.f;
            if ((unsigned)gr < 64u && (unsigned)gc < 64u)
                v = x[((b * 256 + ci) * 64 + gr) * 64 + gc];
            rows[t] = v;
        }
        if (t < 81)
            ((float4*)pwl)[t] = ((const float4*)pwT)[ci * 81 + t];
        __syncthreads();
#pragma unroll
        for (int k9 = 0; k9 < 9; ++k9) {
            int ki = k9 / 3, kj = k9 % 3;
            float xv = rows[ki * 66 + w0 + kj];
#pragma unroll
            for (int c9 = 0; c9 < 9; ++c9)
                acc[c9] += pwl[k9 * 36 + chb + c9] * xv;
        }
    }
#pragma unroll
    for (int c9 = 0; c9 < 9; ++c9) {
        int ch36 = chb + c9;
        int br = ch36 / 18, ch = ch36 % 18;
        float bias = br ? pby[ch] : pbx[ch];
        off[((br * 4 + b) * 18 + ch) * 4096 + h * 64 + w0] = acc[c9] + bias;
    }
}

// ---------- bilinear sampling → bf16 K-panels ----------
// Bpan[kt72][n16384][kw32]  (one branch at a time), k = n9*256+ci
__global__ __launch_bounds__(256) void k_sample(const float* __restrict__ x,
                                                const float* __restrict__ off,
                                                u16* __restrict__ Bpan, int br) {
    int t = threadIdx.x;
    int h = blockIdx.x * 4 + (t >> 6);
    int w = t & 63;
    int b = blockIdx.y;
    int n9 = blockIdx.z;
    int pix = h * 64 + w;

    float offx = off[((br * 4 + b) * 18 + n9) * 4096 + pix];
    float offy = off[((br * 4 + b) * 18 + n9 + 9) * 4096 + pix];
    int ki = n9 / 3, kj = n9 % 3;
    float px = offx + (float)(ki - 1) + (float)(h + 1);
    float py = offy + (float)(kj - 1) + (float)(w + 1);
    float fx = floorf(px), fy = floorf(py);
    int ltx = min(max((int)fx, 0), 65);
    int lty = min(max((int)fy, 0), 65);
    int rbx = min(max((int)fx + 1, 0), 65);
    int rby = min(max((int)fy + 1, 0), 65);
    float pxc = fminf(fmaxf(px, 0.f), 65.f);
    float pyc = fminf(fmaxf(py, 0.f), 65.f);
    float axl = 1.f + ((float)ltx - pxc);
    float axr = 1.f - ((float)rbx - pxc);
    float ayl = 1.f + ((float)lty - pyc);
    float ayr = 1.f - ((float)rby - pyc);
    float glt = axl * ayl, grb = axr * ayr, glb = axl * ayr, grt = axr * ayl;
    int a0 = ltx - 1, b0 = lty - 1, a1 = rbx - 1, b1 = rby - 1;
    bool v00 = (unsigned)a0 < 64u && (unsigned)b0 < 64u;
    bool v11 = (unsigned)a1 < 64u && (unsigned)b1 < 64u;
    bool v01 = (unsigned)a0 < 64u && (unsigned)b1 < 64u;
    bool v10 = (unsigned)a1 < 64u && (unsigned)b0 < 64u;
    int o00 = a0 * 64 + b0, o11 = a1 * 64 + b1;
    int o01 = a0 * 64 + b1, o10 = a1 * 64 + b0;
    const float* xb = x + b * 256 * 4096;

    for (int cb = 0; cb < 8; ++cb) {
        unsigned pk_[16];
#pragma unroll
        for (int p = 0; p < 16; ++p) {
            unsigned lo = 0, hi = 0;
#pragma unroll
            for (int e = 0; e < 2; ++e) {
                int ci = cb * 32 + p * 2 + e;
                const float* ch = xb + ci * 4096;
                float v = 0.f;
                if (v00) v += glt * ch[o00];
                if (v11) v += grb * ch[o11];
                if (v01) v += glb * ch[o01];
                if (v10) v += grt * ch[o10];
                unsigned bf = f2bf(v);
                if (e == 0) lo = bf; else hi = bf;
            }
            pk_[p] = lo | (hi << 16);
        }
        u16* dst = Bpan + ((n9 * 8 + cb) * 16384 + b * 4096 + pix) * 32;
        uint4* d4 = (uint4*)dst;
#pragma unroll
        for (int c = 0; c < 4; ++c)
            d4[c] = make_uint4(pk_[4 * c], pk_[4 * c + 1], pk_[4 * c + 2], pk_[4 * c + 3]);
    }
}

// ---------- deformable-conv GEMM: M=256(co) N=16384 K=2304, bf16 MFMA ----------
// writes output as bf16 K-panels P[kt16][n16384][32] (k = br*256+co) for k_final
__global__ __launch_bounds__(256) void k_gemm_deform(const u16* __restrict__ Apan,
                                                     const u16* __restrict__ Bpan,
                                                     u16* __restrict__ P, int br) {
    __shared__ __align__(16) char lds[34816];   // 2x8KB A + 2x8KB B, reused as E[128][136]
    int t = threadIdx.x;
    int ntile = blockIdx.x, cot = blockIdx.y;
    int wv = t >> 6, l = t & 63;
    int lr = l & 15, lq = l >> 4;
    int wm = (wv >> 1) * 64, wn = (wv & 1) * 64;

    f32x4 acc[4][4];
#pragma unroll
    for (int i = 0; i < 4; ++i)
#pragma unroll
        for (int j = 0; j < 4; ++j) acc[i][j] = (f32x4){0.f, 0.f, 0.f, 0.f};

    auto stg = [&](int buf, int kt) {
        const char* as = (const char*)(Apan + (br * 72 + kt) * 8192 + cot * 4096);
        const char* bs = (const char*)(Bpan + kt * 524288 + ntile * 4096);
        char* al = lds + buf * 8192;
        char* bl = lds + 16384 + buf * 8192;
        gll16(as + wv * 1024 + l * 16, al + wv * 1024);
        gll16(as + 4096 + wv * 1024 + l * 16, al + 4096 + wv * 1024);
        gll16(bs + wv * 1024 + l * 16, bl + wv * 1024);
        gll16(bs + 4096 + wv * 1024 + l * 16, bl + 4096 + wv * 1024);
    };

    stg(0, 0);
    int cur = 0;
    for (int kt = 0; kt < 72; ++kt) {
        __syncthreads();
        if (kt + 1 < 72) stg(cur ^ 1, kt + 1);
        const u16* Ab = (const u16*)(lds + cur * 8192);
        const u16* Bb = (const u16*)(lds + 16384 + cur * 8192);
        bf16x8 af[4], bf[4];
#pragma unroll
        for (int mf = 0; mf < 4; ++mf)
            af[mf] = *(const bf16x8*)(Ab + (wm + mf * 16 + lr) * 32 + lq * 8);
#pragma unroll
        for (int nf = 0; nf < 4; ++nf)
            bf[nf] = *(const bf16x8*)(Bb + (wn + nf * 16 + lr) * 32 + lq * 8);
#pragma unroll
        for (int mf = 0; mf < 4; ++mf)
#pragma unroll
            for (int nf = 0; nf < 4; ++nf)
                acc[mf][nf] = __builtin_amdgcn_mfma_f32_16x16x32_bf16(
                    af[mf], bf[nf], acc[mf][nf], 0, 0, 0);
        cur ^= 1;
    }

    __syncthreads();
    u16 (*E)[136] = (u16(*)[136])lds;           // [n128][m128+pad]
#pragma unroll
    for (int mf = 0; mf < 4; ++mf)
#pragma unroll
        for (int nf = 0; nf < 4; ++nf) {
            int n = wn + nf * 16 + lr;
            int m0 = wm + mf * 16 + lq * 4;
            u16x4 pk;
#pragma unroll
            for (int r = 0; r < 4; ++r)
                pk[r] = (u16)f2bf(acc[mf][nf][r]);
            *(u16x4*)&E[n][m0] = pk;
        }
    __syncthreads();
    int nl = t & 127, kq0 = t >> 7;
    int ktbase = br * 8 + cot * 4;
#pragma unroll
    for (int jj = 0; jj < 2; ++jj) {
        int ktl = kq0 + 2 * jj;
        const uint4* src = (const uint4*)&E[nl][ktl * 32];
        uint4* dst = (uint4*)(P + ((ktbase + ktl) * 16384 + ntile * 128 + nl) * 32);
#pragma unroll
        for (int c = 0; c < 4; ++c) dst[c] = src[c];
    }
}

// ---------- 1x1 conv GEMM: M=256 N=16384 K=512 + bias + residual ----------
__global__ __launch_bounds__(256) void k_gemm_final(const u16* __restrict__ Af,
                                                    const u16* __restrict__ P,
                                                    const float* __restrict__ bo,
                                                    const float* __restrict__ x,
                                                    float* __restrict__ out) {
    __shared__ __align__(16) char lds[32768];
    int t = threadIdx.x;
    int ntile = blockIdx.x, cot = blockIdx.y;
    int wv = t >> 6, l = t & 63;
    int lr = l & 15, lq = l >> 4;
    int wm = (wv >> 1) * 64, wn = (wv & 1) * 64;

    f32x4 acc[4][4];
#pragma unroll
    for (int i = 0; i < 4; ++i)
#pragma unroll
        for (int j = 0; j < 4; ++j) acc[i][j] = (f32x4){0.f, 0.f, 0.f, 0.f};

    auto stg = [&](int buf, int kt) {
        const char* as = (const char*)(Af + kt * 8192 + cot * 4096);
        const char* bs = (const char*)(P + kt * 524288 + ntile * 4096);
        char* al = lds + buf * 8192;
        char* bl = lds + 16384 + buf * 8192;
        gll16(as + wv * 1024 + l * 16, al + wv * 1024);
        gll16(as + 4096 + wv * 1024 + l * 16, al + 4096 + wv * 1024);
        gll16(bs + wv * 1024 + l * 16, bl + wv * 1024);
        gll16(bs + 4096 + wv * 1024 + l * 16, bl + 4096 + wv * 1024);
    };

    stg(0, 0);
    int cur = 0;
    for (int kt = 0; kt < 16; ++kt) {
        __syncthreads();
        if (kt + 1 < 16) stg(cur ^ 1, kt + 1);
        const u16* Ab = (const u16*)(lds + cur * 8192);
        const u16* Bb = (const u16*)(lds + 16384 + cur * 8192);
        bf16x8 af[4], bf[4];
#pragma unroll
        for (int mf = 0; mf < 4; ++mf)
            af[mf] = *(const bf16x8*)(Ab + (wm + mf * 16 + lr) * 32 + lq * 8);
#pragma unroll
        for (int nf = 0; nf < 4; ++nf)
            bf[nf] = *(const bf16x8*)(Bb + (wn + nf * 16 + lr) * 32 + lq * 8);
#pragma unroll
        for (int mf = 0; mf < 4; ++mf)
#pragma unroll
            for (int nf = 0; nf < 4; ++nf)
                acc[mf][nf] = __builtin_amdgcn_mfma_f32_16x16x32_bf16(
                    af[mf], bf[nf], acc[mf][nf], 0, 0, 0);
        cur ^= 1;
    }

#pragma unroll
    for (int mf = 0; mf < 4; ++mf)
#pragma unroll
        for (int nf = 0; nf < 4; ++nf) {
            int co0 = cot * 128 + wm + mf * 16 + lq * 4;
            int n = ntile * 128 + wn + nf * 16 + lr;
            int b = n >> 12, pix = n & 4095;
#pragma unroll
            for (int r = 0; r < 4; ++r) {
                int co = co0 + r;
                int o = (b * 256 + co) * 4096 + pix;
                out[o] = acc[mf][nf][r] + bo[co] + x[o];
            }
        }
}

// -------------------- launch --------------------
extern "C" void kernel_launch(void* const* d_in, const int* in_sizes, int n_in,
                              void* d_out, int out_size, void* d_ws, size_t ws_size,
                              hipStream_t stream) {
    const float* x   = (const float*)d_in[0];
    const float* pwx = (const float*)d_in[1];
    const float* pbx = (const float*)d_in[2];
    const float* wx  = (const float*)d_in[3];
    const float* pwy = (const float*)d_in[4];
    const float* pby = (const float*)d_in[5];
    const float* wy  = (const float*)d_in[6];
    const float* wo  = (const float*)d_in[7];
    const float* bo  = (const float*)d_in[8];
    float* out = (float*)d_out;

    char* ws = (char*)d_ws;
    float* off  = (float*)(ws + 0);          //  2,359,296 B
    float* pwT  = (float*)(ws + 2359296);    //    331,776 B
    u16*   Apan = (u16*)  (ws + 2691072);    //  2,359,296 B
    u16*   Af   = (u16*)  (ws + 5050368);    //    262,144 B
    u16*   P    = (u16*)  (ws + 5312512);    // 16,777,216 B
    u16*   Bpan = (u16*)  (ws + 22089728);   // 75,497,472 B (per-branch, reused)

    k_transpose_pw<<<324,  256, 0, stream>>>(pwx, pwy, pwT);
    k_transpose_w <<<4608, 256, 0, stream>>>(wx, wy, Apan);
    k_transpose_wo<<<512,  256, 0, stream>>>(wo, Af);
    k_offset      <<<dim3(64, 4),    256, 0, stream>>>(x, pwT, pbx, pby, off);

    k_sample      <<<dim3(16, 4, 9), 256, 0, stream>>>(x, off, Bpan, 0);
    k_gemm_deform <<<dim3(128, 2),   256, 0, stream>>>(Apan, Bpan, P, 0);
    k_sample      <<<dim3(16, 4, 9), 256, 0, stream>>>(x, off, Bpan, 1);
    k_gemm_deform <<<dim3(128, 2),   256, 0, stream>>>(Apan, Bpan, P, 1);

    k_gemm_final  <<<dim3(128, 2),   256, 0, stream>>>(Af, P, bo, x, out);
}

// Round 6
// 785.649 us; speedup vs baseline: 1.8203x; 1.4016x over previous
//
#include <hip/hip_runtime.h>

typedef unsigned short u16;
typedef __attribute__((ext_vector_type(8))) short bf16x8;
typedef __attribute__((ext_vector_type(4))) float f32x4;
typedef __attribute__((ext_vector_type(4))) u16 u16x4;

__device__ __forceinline__ unsigned f2bf(float f) {
    unsigned u = __float_as_uint(f);
    return (u + 0x7FFFu + ((u >> 16) & 1u)) >> 16;   // RNE, finite inputs
}

__device__ __forceinline__ void gll16(const void* g, void* l) {
    __builtin_amdgcn_global_load_lds(
        (const __attribute__((address_space(1))) char*)g,
        (__attribute__((address_space(3))) char*)l, 16, 0, 0);
}

// ---------- weight → panel transposes ----------
// Apan[br][kt72][co256][kw32], k = kt*32+kw = n9*256+ci
__global__ void k_transpose_w(const float* __restrict__ wx,
                              const float* __restrict__ wy,
                              u16* __restrict__ Apan) {
    int idx = blockIdx.x * 256 + threadIdx.x;          // < 1179648
    int br = idx / 589824, rem = idx % 589824;
    int kt = rem / 8192, r2 = rem % 8192;
    int co = r2 / 32, kw = r2 % 32;
    int k = kt * 32 + kw, n9 = k >> 8, ci = k & 255;
    const float* w = br ? wy : wx;
    Apan[idx] = (u16)f2bf(w[(co * 256 + ci) * 9 + n9]);
}

// Af[kt16][co256][kw32], k = ch in concat(Cx,Cy)
__global__ void k_transpose_wo(const float* __restrict__ wo, u16* __restrict__ Af) {
    int idx = blockIdx.x * 256 + threadIdx.x;          // < 131072
    int kt = idx / 8192, r2 = idx % 8192;
    int co = r2 / 32, kw = r2 % 32;
    Af[idx] = (u16)f2bf(wo[co * 512 + kt * 32 + kw]);
}

// pwT[ci][n9][ch36] contiguous 324 floats per ci
__global__ void k_transpose_pw(const float* __restrict__ pwx,
                               const float* __restrict__ pwy,
                               float* __restrict__ pwT) {
    int idx  = blockIdx.x * 256 + threadIdx.x;         // < 82944
    int ch36 = idx % 36;
    int t    = idx / 36;
    int n    = t % 9, ci = t / 9;
    int br   = ch36 / 18, ch = ch36 % 18;
    const float* pw = br ? pwy : pwx;
    pwT[idx] = pw[(ch * 256 + ci) * 9 + n];
}

// ---------- offset conv: split-K direct conv, fp32 ----------
// part[ks8][b4][ch36][4096]
__global__ __launch_bounds__(256) void k_offset_sk(const float* __restrict__ x,
                                                   const float* __restrict__ pwT,
                                                   float* __restrict__ part) {
    __shared__ float rows[396];   // [6][66]
    int t = threadIdx.x;
    int h0 = blockIdx.x * 4;
    int b = blockIdx.y, ks = blockIdx.z;
    int r0 = t >> 6, w = t & 63;

    float acc[36];
#pragma unroll
    for (int c = 0; c < 36; ++c) acc[c] = 0.f;

    int ci0 = ks * 32;
    for (int cc = 0; cc < 32; ++cc) {
        int ci = ci0 + cc;
        const float* xc = x + ((b * 256 + ci) * 64) * 64;
        __syncthreads();
        {
            int r = t / 66, c = t % 66;
            int gr = h0 - 1 + r, gc = c - 1;
            float v = 0.f;
            if ((unsigned)gr < 64u && (unsigned)gc < 64u) v = xc[gr * 64 + gc];
            rows[t] = v;
            int t2 = t + 256;
            if (t2 < 396) {
                r = t2 / 66; c = t2 % 66;
                gr = h0 - 1 + r; gc = c - 1;
                v = 0.f;
                if ((unsigned)gr < 64u && (unsigned)gc < 64u) v = xc[gr * 64 + gc];
                rows[t2] = v;
            }
        }
        __syncthreads();
        const float* pw = pwT + ci * 324;   // block-uniform → s_load
#pragma unroll
        for (int k9 = 0; k9 < 9; ++k9) {
            int ki = k9 / 3, kj = k9 % 3;
            float xv = rows[(r0 + ki) * 66 + w + kj];
#pragma unroll
            for (int c = 0; c < 36; ++c)
                acc[c] += pw[k9 * 36 + c] * xv;
        }
    }
    int pix = (h0 + r0) * 64 + w;
#pragma unroll
    for (int c = 0; c < 36; ++c)
        part[((ks * 4 + b) * 36 + c) * 4096 + pix] = acc[c];
}

// off[br][b][ch18][4096] = sum_ks part + bias
__global__ void k_offset_red(const float* __restrict__ part,
                             const float* __restrict__ pbx,
                             const float* __restrict__ pby,
                             float* __restrict__ off) {
    int i = blockIdx.x * 256 + threadIdx.x;   // < 589824
    int pix = i & 4095;
    int ch = (i >> 12) % 18;
    int bb = (i >> 12) / 18;                  // br*4+b
    int br = bb >> 2, b = bb & 3;
    int ch36 = br * 18 + ch;
    float s = br ? pby[ch] : pbx[ch];
#pragma unroll
    for (int ks = 0; ks < 8; ++ks)
        s += part[((ks * 4 + b) * 36 + ch36) * 4096 + pix];
    off[i] = s;
}

// ---------- bilinear sampling → bf16 K-panels ----------
// Bpan[kt72][n16384][kw32]  (one branch at a time), k = n9*256+ci
__global__ __launch_bounds__(256) void k_sample(const float* __restrict__ x,
                                                const float* __restrict__ off,
                                                u16* __restrict__ Bpan, int br) {
    int t = threadIdx.x;
    int h = blockIdx.x * 4 + (t >> 6);
    int w = t & 63;
    int b = blockIdx.y;
    int n9 = blockIdx.z;
    int pix = h * 64 + w;

    float offx = off[((br * 4 + b) * 18 + n9) * 4096 + pix];
    float offy = off[((br * 4 + b) * 18 + n9 + 9) * 4096 + pix];
    int ki = n9 / 3, kj = n9 % 3;
    float px = offx + (float)(ki - 1) + (float)(h + 1);
    float py = offy + (float)(kj - 1) + (float)(w + 1);
    float fx = floorf(px), fy = floorf(py);
    int ltx = min(max((int)fx, 0), 65);
    int lty = min(max((int)fy, 0), 65);
    int rbx = min(max((int)fx + 1, 0), 65);
    int rby = min(max((int)fy + 1, 0), 65);
    float pxc = fminf(fmaxf(px, 0.f), 65.f);
    float pyc = fminf(fmaxf(py, 0.f), 65.f);
    float axl = 1.f + ((float)ltx - pxc);
    float axr = 1.f - ((float)rbx - pxc);
    float ayl = 1.f + ((float)lty - pyc);
    float ayr = 1.f - ((float)rby - pyc);
    float glt = axl * ayl, grb = axr * ayr, glb = axl * ayr, grt = axr * ayl;
    int a0 = ltx - 1, b0 = lty - 1, a1 = rbx - 1, b1 = rby - 1;
    bool v00 = (unsigned)a0 < 64u && (unsigned)b0 < 64u;
    bool v11 = (unsigned)a1 < 64u && (unsigned)b1 < 64u;
    bool v01 = (unsigned)a0 < 64u && (unsigned)b1 < 64u;
    bool v10 = (unsigned)a1 < 64u && (unsigned)b0 < 64u;
    int o00 = a0 * 64 + b0, o11 = a1 * 64 + b1;
    int o01 = a0 * 64 + b1, o10 = a1 * 64 + b0;
    const float* xb = x + b * 256 * 4096;

    for (int cb = 0; cb < 8; ++cb) {
        unsigned pk_[16];
#pragma unroll
        for (int p = 0; p < 16; ++p) {
            unsigned lo = 0, hi = 0;
#pragma unroll
            for (int e = 0; e < 2; ++e) {
                int ci = cb * 32 + p * 2 + e;
                const float* ch = xb + ci * 4096;
                float v = 0.f;
                if (v00) v += glt * ch[o00];
                if (v11) v += grb * ch[o11];
                if (v01) v += glb * ch[o01];
                if (v10) v += grt * ch[o10];
                unsigned bf = f2bf(v);
                if (e == 0) lo = bf; else hi = bf;
            }
            pk_[p] = lo | (hi << 16);
        }
        u16* dst = Bpan + ((n9 * 8 + cb) * 16384 + b * 4096 + pix) * 32;
        uint4* d4 = (uint4*)dst;
#pragma unroll
        for (int c = 0; c < 4; ++c)
            d4[c] = make_uint4(pk_[4 * c], pk_[4 * c + 1], pk_[4 * c + 2], pk_[4 * c + 3]);
    }
}

// ---------- deformable-conv GEMM: tile 128co x 64n, K=2304 ----------
// grid (256 ntiles, 2 cot); writes P[kt16][n16384][32] (k = br*256+co)
__global__ __launch_bounds__(256) void k_gemm_deform(const u16* __restrict__ Apan,
                                                     const u16* __restrict__ Bpan,
                                                     u16* __restrict__ P, int br) {
    __shared__ __align__(16) char lds[24576];   // A 2x8KB @0, B 2x4KB @16384; epi E[64][136]
    int t = threadIdx.x;
    int ntile = blockIdx.x, cot = blockIdx.y;
    int wv = t >> 6, l = t & 63;
    int lr = l & 15, lq = l >> 4;
    int wm = (wv >> 1) * 64, wn = (wv & 1) * 32;

    f32x4 acc[4][2];
#pragma unroll
    for (int i = 0; i < 4; ++i)
#pragma unroll
        for (int j = 0; j < 2; ++j) acc[i][j] = (f32x4){0.f, 0.f, 0.f, 0.f};

    auto stg = [&](int buf, int kt) {
        const char* as = (const char*)(Apan + (br * 72 + kt) * 8192 + cot * 4096);
        const char* bs = (const char*)(Bpan + kt * 524288 + ntile * 2048);
        char* al = lds + buf * 8192;
        char* bl = lds + 16384 + buf * 4096;
        gll16(as + wv * 1024 + l * 16, al + wv * 1024);
        gll16(as + 4096 + wv * 1024 + l * 16, al + 4096 + wv * 1024);
        gll16(bs + wv * 1024 + l * 16, bl + wv * 1024);
    };

    stg(0, 0);
    int cur = 0;
    for (int kt = 0; kt < 72; ++kt) {
        __syncthreads();
        if (kt + 1 < 72) stg(cur ^ 1, kt + 1);
        const u16* Ab = (const u16*)(lds + cur * 8192);
        const u16* Bb = (const u16*)(lds + 16384 + cur * 4096);
        bf16x8 af[4], bfv[2];
#pragma unroll
        for (int mf = 0; mf < 4; ++mf)
            af[mf] = *(const bf16x8*)(Ab + (wm + mf * 16 + lr) * 32 + lq * 8);
#pragma unroll
        for (int nf = 0; nf < 2; ++nf)
            bfv[nf] = *(const bf16x8*)(Bb + (wn + nf * 16 + lr) * 32 + lq * 8);
#pragma unroll
        for (int mf = 0; mf < 4; ++mf)
#pragma unroll
            for (int nf = 0; nf < 2; ++nf)
                acc[mf][nf] = __builtin_amdgcn_mfma_f32_16x16x32_bf16(
                    af[mf], bfv[nf], acc[mf][nf], 0, 0, 0);
        cur ^= 1;
    }

    __syncthreads();
    u16 (*E)[136] = (u16(*)[136])lds;           // [n64][m128+pad]
#pragma unroll
    for (int mf = 0; mf < 4; ++mf)
#pragma unroll
        for (int nf = 0; nf < 2; ++nf) {
            int n = wn + nf * 16 + lr;
            int m0 = wm + mf * 16 + lq * 4;
            u16x4 pk;
#pragma unroll
            for (int r = 0; r < 4; ++r)
                pk[r] = (u16)f2bf(acc[mf][nf][r]);
            *(u16x4*)&E[n][m0] = pk;
        }
    __syncthreads();
    int ktl = t >> 6;                 // 0..3
    int nl = t & 63;
    int ktbase = br * 8 + cot * 4;
    const uint4* src = (const uint4*)&E[nl][ktl * 32];
    uint4* dst = (uint4*)(P + ((ktbase + ktl) * 16384 + ntile * 64 + nl) * 32);
#pragma unroll
    for (int c = 0; c < 4; ++c) dst[c] = src[c];
}

// ---------- 1x1 conv GEMM: tile 128co x 64n, K=512 + bias + residual ----------
__global__ __launch_bounds__(256) void k_gemm_final(const u16* __restrict__ Af,
                                                    const u16* __restrict__ P,
                                                    const float* __restrict__ bo,
                                                    const float* __restrict__ x,
                                                    float* __restrict__ out) {
    __shared__ __align__(16) char lds[24576];
    int t = threadIdx.x;
    int ntile = blockIdx.x, cot = blockIdx.y;
    int wv = t >> 6, l = t & 63;
    int lr = l & 15, lq = l >> 4;
    int wm = (wv >> 1) * 64, wn = (wv & 1) * 32;

    f32x4 acc[4][2];
#pragma unroll
    for (int i = 0; i < 4; ++i)
#pragma unroll
        for (int j = 0; j < 2; ++j) acc[i][j] = (f32x4){0.f, 0.f, 0.f, 0.f};

    auto stg = [&](int buf, int kt) {
        const char* as = (const char*)(Af + kt * 8192 + cot * 4096);
        const char* bs = (const char*)(P + kt * 524288 + ntile * 2048);
        char* al = lds + buf * 8192;
        char* bl = lds + 16384 + buf * 4096;
        gll16(as + wv * 1024 + l * 16, al + wv * 1024);
        gll16(as + 4096 + wv * 1024 + l * 16, al + 4096 + wv * 1024);
        gll16(bs + wv * 1024 + l * 16, bl + wv * 1024);
    };

    stg(0, 0);
    int cur = 0;
    for (int kt = 0; kt < 16; ++kt) {
        __syncthreads();
        if (kt + 1 < 16) stg(cur ^ 1, kt + 1);
        const u16* Ab = (const u16*)(lds + cur * 8192);
        const u16* Bb = (const u16*)(lds + 16384 + cur * 4096);
        bf16x8 af[4], bfv[2];
#pragma unroll
        for (int mf = 0; mf < 4; ++mf)
            af[mf] = *(const bf16x8*)(Ab + (wm + mf * 16 + lr) * 32 + lq * 8);
#pragma unroll
        for (int nf = 0; nf < 2; ++nf)
            bfv[nf] = *(const bf16x8*)(Bb + (wn + nf * 16 + lr) * 32 + lq * 8);
#pragma unroll
        for (int mf = 0; mf < 4; ++mf)
#pragma unroll
            for (int nf = 0; nf < 2; ++nf)
                acc[mf][nf] = __builtin_amdgcn_mfma_f32_16x16x32_bf16(
                    af[mf], bfv[nf], acc[mf][nf], 0, 0, 0);
        cur ^= 1;
    }

#pragma unroll
    for (int mf = 0; mf < 4; ++mf)
#pragma unroll
        for (int nf = 0; nf < 2; ++nf) {
            int co0 = cot * 128 + wm + mf * 16 + lq * 4;
            int n = ntile * 64 + wn + nf * 16 + lr;
            int b = n >> 12, pix = n & 4095;
#pragma unroll
            for (int r = 0; r < 4; ++r) {
                int co = co0 + r;
                int o = (b * 256 + co) * 4096 + pix;
                out[o] = acc[mf][nf][r] + bo[co] + x[o];
            }
        }
}

// -------------------- launch --------------------
extern "C" void kernel_launch(void* const* d_in, const int* in_sizes, int n_in,
                              void* d_out, int out_size, void* d_ws, size_t ws_size,
                              hipStream_t stream) {
    const float* x   = (const float*)d_in[0];
    const float* pwx = (const float*)d_in[1];
    const float* pbx = (const float*)d_in[2];
    const float* wx  = (const float*)d_in[3];
    const float* pwy = (const float*)d_in[4];
    const float* pby = (const float*)d_in[5];
    const float* wy  = (const float*)d_in[6];
    const float* wo  = (const float*)d_in[7];
    const float* bo  = (const float*)d_in[8];
    float* out = (float*)d_out;

    char* ws = (char*)d_ws;
    float* off  = (float*)(ws + 0);          //  2,359,296 B
    float* pwT  = (float*)(ws + 2359296);    //    331,776 B
    u16*   Apan = (u16*)  (ws + 2691072);    //  2,359,296 B
    u16*   Af   = (u16*)  (ws + 5050368);    //    262,144 B
    u16*   P    = (u16*)  (ws + 5312512);    // 16,777,216 B
    u16*   Bpan = (u16*)  (ws + 22089728);   // 75,497,472 B (per-branch, reused)
    float* part = (float*)(ws + 22089728);   // 18,874,368 B — aliases Bpan (dead before k_sample)

    k_transpose_pw<<<324,  256, 0, stream>>>(pwx, pwy, pwT);
    k_transpose_w <<<4608, 256, 0, stream>>>(wx, wy, Apan);
    k_transpose_wo<<<512,  256, 0, stream>>>(wo, Af);

    k_offset_sk   <<<dim3(16, 4, 8), 256, 0, stream>>>(x, pwT, part);
    k_offset_red  <<<2304, 256, 0, stream>>>(part, pbx, pby, off);

    k_sample      <<<dim3(16, 4, 9), 256, 0, stream>>>(x, off, Bpan, 0);
    k_gemm_deform <<<dim3(256, 2),   256, 0, stream>>>(Apan, Bpan, P, 0);
    k_sample      <<<dim3(16, 4, 9), 256, 0, stream>>>(x, off, Bpan, 1);
    k_gemm_deform <<<dim3(256, 2),   256, 0, stream>>>(Apan, Bpan, P, 1);

    k_gemm_final  <<<dim3(256, 2),   256, 0, stream>>>(Af, P, bo, x, out);
}

// Round 8
// 582.799 us; speedup vs baseline: 2.4538x; 1.3481x over previous
//
#include <hip/hip_runtime.h>

typedef unsigned short u16;
typedef __attribute__((ext_vector_type(8))) short bf16x8;
typedef __attribute__((ext_vector_type(4))) float f32x4;
typedef __attribute__((ext_vector_type(4))) u16 u16x4;

__device__ __forceinline__ unsigned f2bf(float f) {
    unsigned u = __float_as_uint(f);
    return (u + 0x7FFFu + ((u >> 16) & 1u)) >> 16;   // RNE, finite inputs
}

__device__ __forceinline__ void gll16(const void* g, void* l) {
    __builtin_amdgcn_global_load_lds(
        (const __attribute__((address_space(1))) char*)g,
        (__attribute__((address_space(3))) char*)l, 16, 0, 0);
}

// ---------- weight → panel transposes ----------
// Apan[br][kt72][co256][kw32], k = kt*32+kw = n9*256+ci
__global__ void k_transpose_w(const float* __restrict__ wx,
                              const float* __restrict__ wy,
                              u16* __restrict__ Apan) {
    int idx = blockIdx.x * 256 + threadIdx.x;          // < 1179648
    int br = idx / 589824, rem = idx % 589824;
    int kt = rem / 8192, r2 = rem % 8192;
    int co = r2 / 32, kw = r2 % 32;
    int k = kt * 32 + kw, n9 = k >> 8, ci = k & 255;
    const float* w = br ? wy : wx;
    Apan[idx] = (u16)f2bf(w[(co * 256 + ci) * 9 + n9]);
}

// Af[kt16][co256][kw32], k = ch in concat(Cx,Cy)
__global__ void k_transpose_wo(const float* __restrict__ wo, u16* __restrict__ Af) {
    int idx = blockIdx.x * 256 + threadIdx.x;          // < 131072
    int kt = idx / 8192, r2 = idx % 8192;
    int co = r2 / 32, kw = r2 % 32;
    Af[idx] = (u16)f2bf(wo[co * 512 + kt * 32 + kw]);
}

// pwT[ci][n9][ch36] contiguous 324 floats per ci
__global__ void k_transpose_pw(const float* __restrict__ pwx,
                               const float* __restrict__ pwy,
                               float* __restrict__ pwT) {
    int idx  = blockIdx.x * 256 + threadIdx.x;         // < 82944
    int ch36 = idx % 36;
    int t    = idx / 36;
    int n    = t % 9, ci = t / 9;
    int br   = ch36 / 18, ch = ch36 % 18;
    const float* pw = br ? pwy : pwx;
    pwT[idx] = pw[(ch * 256 + ci) * 9 + n];
}

// ---------- padded NHWC transpose: xT[b][66][66][256] (border pre-zeroed) ----------
__global__ __launch_bounds__(256) void k_transpose_x(const float* __restrict__ x,
                                                     float* __restrict__ xT) {
    __shared__ float lds[256 * 65];
    int h = blockIdx.x, b = blockIdx.y;
    int t = threadIdx.x;
    int ci0 = t >> 6, w0 = t & 63;
#pragma unroll 4
    for (int it = 0; it < 64; ++it) {
        int ci = it * 4 + ci0;
        lds[ci * 65 + w0] = x[((b * 256 + ci) * 64 + h) * 64 + w0];
    }
    __syncthreads();
    float* dstrow = xT + (size_t)b * 1115136 + ((h + 1) * 66 + 1) * 256;
#pragma unroll 4
    for (int it = 0; it < 64; ++it)
        dstrow[it * 256 + t] = lds[t * 65 + it];
}

// ---------- offset conv: split-K direct conv, fp32 ----------
// part[ks8][b4][ch36][4096]
__global__ __launch_bounds__(256) void k_offset_sk(const float* __restrict__ x,
                                                   const float* __restrict__ pwT,
                                                   float* __restrict__ part) {
    __shared__ float rows[396];   // [6][66]
    int t = threadIdx.x;
    int h0 = blockIdx.x * 4;
    int b = blockIdx.y, ks = blockIdx.z;
    int r0 = t >> 6, w = t & 63;

    float acc[36];
#pragma unroll
    for (int c = 0; c < 36; ++c) acc[c] = 0.f;

    int ci0 = ks * 32;
    for (int cc = 0; cc < 32; ++cc) {
        int ci = ci0 + cc;
        const float* xc = x + ((b * 256 + ci) * 64) * 64;
        __syncthreads();
        {
            int r = t / 66, c = t % 66;
            int gr = h0 - 1 + r, gc = c - 1;
            float v = 0.f;
            if ((unsigned)gr < 64u && (unsigned)gc < 64u) v = xc[gr * 64 + gc];
            rows[t] = v;
            int t2 = t + 256;
            if (t2 < 396) {
                r = t2 / 66; c = t2 % 66;
                gr = h0 - 1 + r; gc = c - 1;
                v = 0.f;
                if ((unsigned)gr < 64u && (unsigned)gc < 64u) v = xc[gr * 64 + gc];
                rows[t2] = v;
            }
        }
        __syncthreads();
        const float* pw = pwT + ci * 324;   // block-uniform → s_load
#pragma unroll
        for (int k9 = 0; k9 < 9; ++k9) {
            int ki = k9 / 3, kj = k9 % 3;
            float xv = rows[(r0 + ki) * 66 + w + kj];
#pragma unroll
            for (int c = 0; c < 36; ++c)
                acc[c] += pw[k9 * 36 + c] * xv;
        }
    }
    int pix = (h0 + r0) * 64 + w;
#pragma unroll
    for (int c = 0; c < 36; ++c)
        part[((ks * 4 + b) * 36 + c) * 4096 + pix] = acc[c];
}

// off[br][b][ch18][4096] = sum_ks part + bias
__global__ void k_offset_red(const float* __restrict__ part,
                             const float* __restrict__ pbx,
                             const float* __restrict__ pby,
                             float* __restrict__ off) {
    int i = blockIdx.x * 256 + threadIdx.x;   // < 589824
    int pix = i & 4095;
    int ch = (i >> 12) % 18;
    int bb = (i >> 12) / 18;                  // br*4+b
    int br = bb >> 2, b = bb & 3;
    int ch36 = br * 18 + ch;
    float s = br ? pby[ch] : pbx[ch];
#pragma unroll
    for (int ks = 0; ks < 8; ++ks)
        s += part[((ks * 4 + b) * 36 + ch36) * 4096 + pix];
    off[i] = s;
}

// ---------- bilinear sampling from NHWC xT → bf16 K-panels ----------
// Bpan_half[kt72][n8192][kw32]; n = bloc*4096+pix (b = bp*2+bloc)
__global__ __launch_bounds__(256) void k_sample_t(const float* __restrict__ xT,
                                                  const float* __restrict__ off,
                                                  u16* __restrict__ Bpan,
                                                  int br, int bp) {
    int t = threadIdx.x;
    int h = blockIdx.x * 4 + (t >> 6);
    int w = t & 63;
    int bloc = blockIdx.y;
    int b = bp * 2 + bloc;
    int z = blockIdx.z;               // 0..35
    int n9 = z % 9, quarter = z / 9;
    int pix = h * 64 + w;

    float offx = off[((br * 4 + b) * 18 + n9) * 4096 + pix];
    float offy = off[((br * 4 + b) * 18 + n9 + 9) * 4096 + pix];
    int ki = n9 / 3, kj = n9 % 3;
    float px = offx + (float)(ki - 1) + (float)(h + 1);
    float py = offy + (float)(kj - 1) + (float)(w + 1);
    float fx = floorf(px), fy = floorf(py);
    int ltx = min(max((int)fx, 0), 65);
    int lty = min(max((int)fy, 0), 65);
    int rbx = min(max((int)fx + 1, 0), 65);
    int rby = min(max((int)fy + 1, 0), 65);
    float pxc = fminf(fmaxf(px, 0.f), 65.f);
    float pyc = fminf(fmaxf(py, 0.f), 65.f);
    float axl = 1.f + ((float)ltx - pxc);
    float axr = 1.f - ((float)rbx - pxc);
    float ayl = 1.f + ((float)lty - pyc);
    float ayr = 1.f - ((float)rby - pyc);
    float glt = axl * ayl, grb = axr * ayr, glb = axl * ayr, grt = axr * ayl;

    const float* base = xT + (size_t)b * 1115136 + quarter * 64;   // 66*66*256
    const float4* p00 = (const float4*)(base + (ltx * 66 + lty) * 256);
    const float4* p11 = (const float4*)(base + (rbx * 66 + rby) * 256);
    const float4* p01 = (const float4*)(base + (ltx * 66 + rby) * 256);
    const float4* p10 = (const float4*)(base + (rbx * 66 + lty) * 256);

    // 64 channels: 8 octs of 8
#pragma unroll
    for (int oct = 0; oct < 8; ++oct) {
        unsigned r[4];
#pragma unroll
        for (int q = 0; q < 2; ++q) {
            int cg = oct * 2 + q;
            float4 a = p00[cg], bb = p11[cg], c = p01[cg], d = p10[cg];
            float f0 = glt * a.x + grb * bb.x + glb * c.x + grt * d.x;
            float f1 = glt * a.y + grb * bb.y + glb * c.y + grt * d.y;
            float f2 = glt * a.z + grb * bb.z + glb * c.z + grt * d.z;
            float f3 = glt * a.w + grb * bb.w + glb * c.w + grt * d.w;
            r[q * 2]     = f2bf(f0) | (f2bf(f1) << 16);
            r[q * 2 + 1] = f2bf(f2) | (f2bf(f3) << 16);
        }
        int ci = quarter * 64 + oct * 8;
        int kt = n9 * 8 + (ci >> 5);
        int kw = ci & 31;
        uint4* dst = (uint4*)(Bpan + (kt * 8192 + bloc * 4096 + pix) * 32 + kw);
        *dst = make_uint4(r[0], r[1], r[2], r[3]);
    }
}

// ---------- deformable-conv GEMM: tile 128co x 64n, K=2304, N=8192 per launch ----------
// grid (128 ntiles, 2 cot); writes P[kt16][n16384][32] (k = br*256+co) at n-offset bp*8192
__global__ __launch_bounds__(256) void k_gemm_deform(const u16* __restrict__ Apan,
                                                     const u16* __restrict__ Bpan,
                                                     u16* __restrict__ P,
                                                     int br, int bp) {
    __shared__ __align__(16) char lds[24576];   // A 2x8KB @0, B 2x4KB @16384; epi E[64][136]
    int t = threadIdx.x;
    int ntile = blockIdx.x, cot = blockIdx.y;
    int wv = t >> 6, l = t & 63;
    int lr = l & 15, lq = l >> 4;
    int wm = (wv >> 1) * 64, wn = (wv & 1) * 32;

    f32x4 acc[4][2];
#pragma unroll
    for (int i = 0; i < 4; ++i)
#pragma unroll
        for (int j = 0; j < 2; ++j) acc[i][j] = (f32x4){0.f, 0.f, 0.f, 0.f};

    auto stg = [&](int buf, int kt) {
        const char* as = (const char*)(Apan + (br * 72 + kt) * 8192 + cot * 4096);
        const char* bs = (const char*)(Bpan + kt * 262144 + ntile * 2048);
        char* al = lds + buf * 8192;
        char* bl = lds + 16384 + buf * 4096;
        gll16(as + wv * 1024 + l * 16, al + wv * 1024);
        gll16(as + 4096 + wv * 1024 + l * 16, al + 4096 + wv * 1024);
        gll16(bs + wv * 1024 + l * 16, bl + wv * 1024);
    };

    stg(0, 0);
    int cur = 0;
    for (int kt = 0; kt < 72; ++kt) {
        __syncthreads();
        if (kt + 1 < 72) stg(cur ^ 1, kt + 1);
        const u16* Ab = (const u16*)(lds + cur * 8192);
        const u16* Bb = (const u16*)(lds + 16384 + cur * 4096);
        bf16x8 af[4], bfv[2];
#pragma unroll
        for (int mf = 0; mf < 4; ++mf)
            af[mf] = *(const bf16x8*)(Ab + (wm + mf * 16 + lr) * 32 + lq * 8);
#pragma unroll
        for (int nf = 0; nf < 2; ++nf)
            bfv[nf] = *(const bf16x8*)(Bb + (wn + nf * 16 + lr) * 32 + lq * 8);
#pragma unroll
        for (int mf = 0; mf < 4; ++mf)
#pragma unroll
            for (int nf = 0; nf < 2; ++nf)
                acc[mf][nf] = __builtin_amdgcn_mfma_f32_16x16x32_bf16(
                    af[mf], bfv[nf], acc[mf][nf], 0, 0, 0);
        cur ^= 1;
    }

    __syncthreads();
    u16 (*E)[136] = (u16(*)[136])lds;           // [n64][m128+pad]
#pragma unroll
    for (int mf = 0; mf < 4; ++mf)
#pragma unroll
        for (int nf = 0; nf < 2; ++nf) {
            int n = wn + nf * 16 + lr;
            int m0 = wm + mf * 16 + lq * 4;
            u16x4 pk;
#pragma unroll
            for (int r = 0; r < 4; ++r)
                pk[r] = (u16)f2bf(acc[mf][nf][r]);
            *(u16x4*)&E[n][m0] = pk;
        }
    __syncthreads();
    int ktl = t >> 6;                 // 0..3
    int nl = t & 63;
    int ktbase = br * 8 + cot * 4;
    const uint4* src = (const uint4*)&E[nl][ktl * 32];
    uint4* dst = (uint4*)(P + ((ktbase + ktl) * 16384 + bp * 8192 + ntile * 64 + nl) * 32);
#pragma unroll
    for (int c = 0; c < 4; ++c) dst[c] = src[c];
}

// ---------- 1x1 conv GEMM: tile 128co x 64n, K=512 + bias + residual ----------
__global__ __launch_bounds__(256) void k_gemm_final(const u16* __restrict__ Af,
                                                    const u16* __restrict__ P,
                                                    const float* __restrict__ bo,
                                                    const float* __restrict__ x,
                                                    float* __restrict__ out) {
    __shared__ __align__(16) char lds[24576];
    int t = threadIdx.x;
    int ntile = blockIdx.x, cot = blockIdx.y;
    int wv = t >> 6, l = t & 63;
    int lr = l & 15, lq = l >> 4;
    int wm = (wv >> 1) * 64, wn = (wv & 1) * 32;

    f32x4 acc[4][2];
#pragma unroll
    for (int i = 0; i < 4; ++i)
#pragma unroll
        for (int j = 0; j < 2; ++j) acc[i][j] = (f32x4){0.f, 0.f, 0.f, 0.f};

    auto stg = [&](int buf, int kt) {
        const char* as = (const char*)(Af + kt * 8192 + cot * 4096);
        const char* bs = (const char*)(P + kt * 524288 + ntile * 2048);
        char* al = lds + buf * 8192;
        char* bl = lds + 16384 + buf * 4096;
        gll16(as + wv * 1024 + l * 16, al + wv * 1024);
        gll16(as + 4096 + wv * 1024 + l * 16, al + 4096 + wv * 1024);
        gll16(bs + wv * 1024 + l * 16, bl + wv * 1024);
    };

    stg(0, 0);
    int cur = 0;
    for (int kt = 0; kt < 16; ++kt) {
        __syncthreads();
        if (kt + 1 < 16) stg(cur ^ 1, kt + 1);
        const u16* Ab = (const u16*)(lds + cur * 8192);
        const u16* Bb = (const u16*)(lds + 16384 + cur * 4096);
        bf16x8 af[4], bfv[2];
#pragma unroll
        for (int mf = 0; mf < 4; ++mf)
            af[mf] = *(const bf16x8*)(Ab + (wm + mf * 16 + lr) * 32 + lq * 8);
#pragma unroll
        for (int nf = 0; nf < 2; ++nf)
            bfv[nf] = *(const bf16x8*)(Bb + (wn + nf * 16 + lr) * 32 + lq * 8);
#pragma unroll
        for (int mf = 0; mf < 4; ++mf)
#pragma unroll
            for (int nf = 0; nf < 2; ++nf)
                acc[mf][nf] = __builtin_amdgcn_mfma_f32_16x16x32_bf16(
                    af[mf], bfv[nf], acc[mf][nf], 0, 0, 0);
        cur ^= 1;
    }

#pragma unroll
    for (int mf = 0; mf < 4; ++mf)
#pragma unroll
        for (int nf = 0; nf < 2; ++nf) {
            int co0 = cot * 128 + wm + mf * 16 + lq * 4;
            int n = ntile * 64 + wn + nf * 16 + lr;
            int b = n >> 12, pix = n & 4095;
#pragma unroll
            for (int r = 0; r < 4; ++r) {
                int co = co0 + r;
                int o = (b * 256 + co) * 4096 + pix;
                out[o] = acc[mf][nf][r] + bo[co] + x[o];
            }
        }
}

// -------------------- launch --------------------
extern "C" void kernel_launch(void* const* d_in, const int* in_sizes, int n_in,
                              void* d_out, int out_size, void* d_ws, size_t ws_size,
                              hipStream_t stream) {
    const float* x   = (const float*)d_in[0];
    const float* pwx = (const float*)d_in[1];
    const float* pbx = (const float*)d_in[2];
    const float* wx  = (const float*)d_in[3];
    const float* pwy = (const float*)d_in[4];
    const float* pby = (const float*)d_in[5];
    const float* wy  = (const float*)d_in[6];
    const float* wo  = (const float*)d_in[7];
    const float* bo  = (const float*)d_in[8];
    float* out = (float*)d_out;

    char* ws = (char*)d_ws;
    float* off  = (float*)(ws + 0);          //  2,359,296 B
    float* pwT  = (float*)(ws + 2359296);    //    331,776 B
    u16*   Apan = (u16*)  (ws + 2691072);    //  2,359,296 B
    u16*   Af   = (u16*)  (ws + 5050368);    //    262,144 B
    u16*   P    = (u16*)  (ws + 5312512);    // 16,777,216 B
    u16*   Bpan = (u16*)  (ws + 22089728);   // 37,748,736 B (half-batch, reused 4x)
    float* part = (float*)(ws + 22089728);   // 18,874,368 B — aliases Bpan (dead before k_sample)
    float* xT   = (float*)(ws + 59838464);   // 17,842,176 B  (4 x 66x66x256 fp32)
    // total 77,680,640 B

    k_transpose_pw<<<324,  256, 0, stream>>>(pwx, pwy, pwT);
    k_transpose_w <<<4608, 256, 0, stream>>>(wx, wy, Apan);
    k_transpose_wo<<<512,  256, 0, stream>>>(wo, Af);

    hipMemsetAsync(xT, 0, 17842176, stream);
    k_transpose_x <<<dim3(64, 4),    256, 0, stream>>>(x, xT);

    k_offset_sk   <<<dim3(16, 4, 8), 256, 0, stream>>>(x, pwT, part);
    k_offset_red  <<<2304, 256, 0, stream>>>(part, pbx, pby, off);

    for (int br = 0; br < 2; ++br)
        for (int bp = 0; bp < 2; ++bp) {
            k_sample_t    <<<dim3(16, 2, 36), 256, 0, stream>>>(xT, off, Bpan, br, bp);
            k_gemm_deform <<<dim3(128, 2),    256, 0, stream>>>(Apan, Bpan, P, br, bp);
        }

    k_gemm_final  <<<dim3(256, 2),   256, 0, stream>>>(Af, P, bo, x, out);
}

// Round 9
// 509.506 us; speedup vs baseline: 2.8068x; 1.1439x over previous
//
#include <hip/hip_runtime.h>

typedef unsigned short u16;
typedef __attribute__((ext_vector_type(8))) short bf16x8;
typedef __attribute__((ext_vector_type(4))) float f32x4;
typedef __attribute__((ext_vector_type(4))) u16 u16x4;

__device__ __forceinline__ unsigned f2bf(float f) {
    unsigned u = __float_as_uint(f);
    return (u + 0x7FFFu + ((u >> 16) & 1u)) >> 16;   // RNE, finite inputs
}

__device__ __forceinline__ void gll16(const void* g, void* l) {
    __builtin_amdgcn_global_load_lds(
        (const __attribute__((address_space(1))) char*)g,
        (__attribute__((address_space(3))) char*)l, 16, 0, 0);
}

// ---------- weight → panel transposes ----------
// Apan[br][kt72][co256][kw32], k = kt*32+kw = n9*256+ci
__global__ void k_transpose_w(const float* __restrict__ wx,
                              const float* __restrict__ wy,
                              u16* __restrict__ Apan) {
    int idx = blockIdx.x * 256 + threadIdx.x;          // < 1179648
    int br = idx / 589824, rem = idx % 589824;
    int kt = rem / 8192, r2 = rem % 8192;
    int co = r2 / 32, kw = r2 % 32;
    int k = kt * 32 + kw, n9 = k >> 8, ci = k & 255;
    const float* w = br ? wy : wx;
    Apan[idx] = (u16)f2bf(w[(co * 256 + ci) * 9 + n9]);
}

// Af[kt16][co256][kw32], k = ch in concat(Cx,Cy)
__global__ void k_transpose_wo(const float* __restrict__ wo, u16* __restrict__ Af) {
    int idx = blockIdx.x * 256 + threadIdx.x;          // < 131072
    int kt = idx / 8192, r2 = idx % 8192;
    int co = r2 / 32, kw = r2 % 32;
    Af[idx] = (u16)f2bf(wo[co * 512 + kt * 32 + kw]);
}

// Aoff[kt72][m64][kw32]: m = ch36 (0..17 branch x, 18..35 branch y), rows 36..63 zero
__global__ void k_transpose_aoff(const float* __restrict__ pwx,
                                 const float* __restrict__ pwy,
                                 u16* __restrict__ Aoff) {
    int idx = blockIdx.x * 256 + threadIdx.x;          // < 147456
    int kt = idx / 2048, r2 = idx % 2048;
    int m = r2 / 32, kw = r2 % 32;
    int k = kt * 32 + kw, n9 = k >> 8, ci = k & 255;
    float v = 0.f;
    if (m < 18)      v = pwx[(m * 256 + ci) * 9 + n9];
    else if (m < 36) v = pwy[((m - 18) * 256 + ci) * 9 + n9];
    Aoff[idx] = (u16)f2bf(v);
}

// ---------- padded NHWC transpose: xT fp32 + xTb bf16, [b][66][66][256], border pre-zeroed ----------
__global__ __launch_bounds__(256) void k_transpose_x(const float* __restrict__ x,
                                                     float* __restrict__ xT,
                                                     u16* __restrict__ xTb) {
    __shared__ float lds[256 * 65];
    int h = blockIdx.x, b = blockIdx.y;
    int t = threadIdx.x;
    int ci0 = t >> 6, w0 = t & 63;
#pragma unroll 4
    for (int it = 0; it < 64; ++it) {
        int ci = it * 4 + ci0;
        lds[ci * 65 + w0] = x[((b * 256 + ci) * 64 + h) * 64 + w0];
    }
    __syncthreads();
    float* dstrow = xT  + (size_t)b * 1115136 + ((h + 1) * 66 + 1) * 256;
    u16*   dstb   = xTb + (size_t)b * 1115136 + ((h + 1) * 66 + 1) * 256;
#pragma unroll 4
    for (int it = 0; it < 64; ++it) {
        float v = lds[t * 65 + it];
        dstrow[it * 256 + t] = v;
        dstb[it * 256 + t]   = (u16)f2bf(v);
    }
}

// ---------- offset conv as MFMA GEMM: M=64(36 real) x N=64pix x K=2304, B direct from xTb ----------
// grid (64 h, 4 b); writes off[br][b][ch18][4096] fp32 (+bias)
__global__ __launch_bounds__(256) void k_offset_gemm(const u16* __restrict__ Aoff,
                                                     const u16* __restrict__ xTb,
                                                     const float* __restrict__ pbx,
                                                     const float* __restrict__ pby,
                                                     float* __restrict__ off) {
    __shared__ __align__(16) char lds[16384];   // A 2x4KB @0, B 2x4KB @8192
    int t = threadIdx.x;
    int h = blockIdx.x, b = blockIdx.y;
    int wv = t >> 6, l = t & 63;
    int lr = l & 15, lq = l >> 4;
    int wm = (wv >> 1) * 32, wn = (wv & 1) * 32;
    const u16* xb = xTb + (size_t)b * 1115136;
    int w = t >> 2, kwq = t & 3;                 // B staging coords (pixel, 8-ch group)

    f32x4 acc[2][2];
#pragma unroll
    for (int i = 0; i < 2; ++i)
#pragma unroll
        for (int j = 0; j < 2; ++j) acc[i][j] = (f32x4){0.f, 0.f, 0.f, 0.f};

    auto stg = [&](int buf, int kt) {
        int n9 = kt >> 3, ci0 = (kt & 7) * 32;
        int ki = n9 / 3, kj = n9 % 3;
        gll16(Aoff + kt * 2048 + t * 8, lds + buf * 4096 + wv * 1024);
        const u16* bs = xb + ((h + ki) * 66 + (w + kj)) * 256 + ci0 + kwq * 8;
        gll16(bs, lds + 8192 + buf * 4096 + wv * 1024);
    };

    stg(0, 0);
    int cur = 0;
    for (int kt = 0; kt < 72; ++kt) {
        __syncthreads();
        if (kt + 1 < 72) stg(cur ^ 1, kt + 1);
        const u16* Ab = (const u16*)(lds + cur * 4096);
        const u16* Bb = (const u16*)(lds + 8192 + cur * 4096);
        bf16x8 af[2], bfv[2];
#pragma unroll
        for (int mf = 0; mf < 2; ++mf)
            af[mf] = *(const bf16x8*)(Ab + (wm + mf * 16 + lr) * 32 + lq * 8);
#pragma unroll
        for (int nf = 0; nf < 2; ++nf)
            bfv[nf] = *(const bf16x8*)(Bb + (wn + nf * 16 + lr) * 32 + lq * 8);
#pragma unroll
        for (int mf = 0; mf < 2; ++mf)
#pragma unroll
            for (int nf = 0; nf < 2; ++nf)
                acc[mf][nf] = __builtin_amdgcn_mfma_f32_16x16x32_bf16(
                    af[mf], bfv[nf], acc[mf][nf], 0, 0, 0);
        cur ^= 1;
    }

#pragma unroll
    for (int mf = 0; mf < 2; ++mf)
#pragma unroll
        for (int nf = 0; nf < 2; ++nf) {
            int m0 = wm + mf * 16 + lq * 4;
            int pix = h * 64 + wn + nf * 16 + lr;
#pragma unroll
            for (int r = 0; r < 4; ++r) {
                int m = m0 + r;
                if (m < 36) {
                    int br = m / 18, ch = m % 18;
                    float bias = br ? pby[ch] : pbx[ch];
                    off[((br * 4 + b) * 18 + ch) * 4096 + pix] = acc[mf][nf][r] + bias;
                }
            }
        }
}

// ---------- bilinear sampling from NHWC xT → bf16 K-panels ----------
// Bpan_half[kt72][n8192][kw32]; n = bloc*4096+pix (b = bp*2+bloc)
__global__ __launch_bounds__(256) void k_sample_t(const float* __restrict__ xT,
                                                  const float* __restrict__ off,
                                                  u16* __restrict__ Bpan,
                                                  int br, int bp) {
    int t = threadIdx.x;
    int h = blockIdx.x * 4 + (t >> 6);
    int w = t & 63;
    int bloc = blockIdx.y;
    int b = bp * 2 + bloc;
    int z = blockIdx.z;               // 0..35
    int n9 = z % 9, quarter = z / 9;
    int pix = h * 64 + w;

    float offx = off[((br * 4 + b) * 18 + n9) * 4096 + pix];
    float offy = off[((br * 4 + b) * 18 + n9 + 9) * 4096 + pix];
    int ki = n9 / 3, kj = n9 % 3;
    float px = offx + (float)(ki - 1) + (float)(h + 1);
    float py = offy + (float)(kj - 1) + (float)(w + 1);
    float fx = floorf(px), fy = floorf(py);
    int ltx = min(max((int)fx, 0), 65);
    int lty = min(max((int)fy, 0), 65);
    int rbx = min(max((int)fx + 1, 0), 65);
    int rby = min(max((int)fy + 1, 0), 65);
    float pxc = fminf(fmaxf(px, 0.f), 65.f);
    float pyc = fminf(fmaxf(py, 0.f), 65.f);
    float axl = 1.f + ((float)ltx - pxc);
    float axr = 1.f - ((float)rbx - pxc);
    float ayl = 1.f + ((float)lty - pyc);
    float ayr = 1.f - ((float)rby - pyc);
    float glt = axl * ayl, grb = axr * ayr, glb = axl * ayr, grt = axr * ayl;

    const float* base = xT + (size_t)b * 1115136 + quarter * 64;   // 66*66*256
    const float4* p00 = (const float4*)(base + (ltx * 66 + lty) * 256);
    const float4* p11 = (const float4*)(base + (rbx * 66 + rby) * 256);
    const float4* p01 = (const float4*)(base + (ltx * 66 + rby) * 256);
    const float4* p10 = (const float4*)(base + (rbx * 66 + lty) * 256);

    // 64 channels: 8 octs of 8
#pragma unroll
    for (int oct = 0; oct < 8; ++oct) {
        unsigned r[4];
#pragma unroll
        for (int q = 0; q < 2; ++q) {
            int cg = oct * 2 + q;
            float4 a = p00[cg], bb = p11[cg], c = p01[cg], d = p10[cg];
            float f0 = glt * a.x + grb * bb.x + glb * c.x + grt * d.x;
            float f1 = glt * a.y + grb * bb.y + glb * c.y + grt * d.y;
            float f2 = glt * a.z + grb * bb.z + glb * c.z + grt * d.z;
            float f3 = glt * a.w + grb * bb.w + glb * c.w + grt * d.w;
            r[q * 2]     = f2bf(f0) | (f2bf(f1) << 16);
            r[q * 2 + 1] = f2bf(f2) | (f2bf(f3) << 16);
        }
        int ci = quarter * 64 + oct * 8;
        int kt = n9 * 8 + (ci >> 5);
        int kw = ci & 31;
        uint4* dst = (uint4*)(Bpan + (kt * 8192 + bloc * 4096 + pix) * 32 + kw);
        *dst = make_uint4(r[0], r[1], r[2], r[3]);
    }
}

// ---------- deformable-conv GEMM: tile 128co x 64n, K=2304, N=8192 per launch ----------
// grid (128 ntiles, 2 cot); writes P[kt16][n16384][32] (k = br*256+co) at n-offset bp*8192
__global__ __launch_bounds__(256) void k_gemm_deform(const u16* __restrict__ Apan,
                                                     const u16* __restrict__ Bpan,
                                                     u16* __restrict__ P,
                                                     int br, int bp) {
    __shared__ __align__(16) char lds[24576];   // A 2x8KB @0, B 2x4KB @16384; epi E[64][136]
    int t = threadIdx.x;
    int ntile = blockIdx.x, cot = blockIdx.y;
    int wv = t >> 6, l = t & 63;
    int lr = l & 15, lq = l >> 4;
    int wm = (wv >> 1) * 64, wn = (wv & 1) * 32;

    f32x4 acc[4][2];
#pragma unroll
    for (int i = 0; i < 4; ++i)
#pragma unroll
        for (int j = 0; j < 2; ++j) acc[i][j] = (f32x4){0.f, 0.f, 0.f, 0.f};

    auto stg = [&](int buf, int kt) {
        const char* as = (const char*)(Apan + (br * 72 + kt) * 8192 + cot * 4096);
        const char* bs = (const char*)(Bpan + kt * 262144 + ntile * 2048);
        char* al = lds + buf * 8192;
        char* bl = lds + 16384 + buf * 4096;
        gll16(as + wv * 1024 + l * 16, al + wv * 1024);
        gll16(as + 4096 + wv * 1024 + l * 16, al + 4096 + wv * 1024);
        gll16(bs + wv * 1024 + l * 16, bl + wv * 1024);
    };

    stg(0, 0);
    int cur = 0;
    for (int kt = 0; kt < 72; ++kt) {
        __syncthreads();
        if (kt + 1 < 72) stg(cur ^ 1, kt + 1);
        const u16* Ab = (const u16*)(lds + cur * 8192);
        const u16* Bb = (const u16*)(lds + 16384 + cur * 4096);
        bf16x8 af[4], bfv[2];
#pragma unroll
        for (int mf = 0; mf < 4; ++mf)
            af[mf] = *(const bf16x8*)(Ab + (wm + mf * 16 + lr) * 32 + lq * 8);
#pragma unroll
        for (int nf = 0; nf < 2; ++nf)
            bfv[nf] = *(const bf16x8*)(Bb + (wn + nf * 16 + lr) * 32 + lq * 8);
#pragma unroll
        for (int mf = 0; mf < 4; ++mf)
#pragma unroll
            for (int nf = 0; nf < 2; ++nf)
                acc[mf][nf] = __builtin_amdgcn_mfma_f32_16x16x32_bf16(
                    af[mf], bfv[nf], acc[mf][nf], 0, 0, 0);
        cur ^= 1;
    }

    __syncthreads();
    u16 (*E)[136] = (u16(*)[136])lds;           // [n64][m128+pad]
#pragma unroll
    for (int mf = 0; mf < 4; ++mf)
#pragma unroll
        for (int nf = 0; nf < 2; ++nf) {
            int n = wn + nf * 16 + lr;
            int m0 = wm + mf * 16 + lq * 4;
            u16x4 pk;
#pragma unroll
            for (int r = 0; r < 4; ++r)
                pk[r] = (u16)f2bf(acc[mf][nf][r]);
            *(u16x4*)&E[n][m0] = pk;
        }
    __syncthreads();
    int ktl = t >> 6;                 // 0..3
    int nl = t & 63;
    int ktbase = br * 8 + cot * 4;
    const uint4* src = (const uint4*)&E[nl][ktl * 32];
    uint4* dst = (uint4*)(P + ((ktbase + ktl) * 16384 + bp * 8192 + ntile * 64 + nl) * 32);
#pragma unroll
    for (int c = 0; c < 4; ++c) dst[c] = src[c];
}

// ---------- 1x1 conv GEMM: tile 128co x 64n, K=512 + bias + residual ----------
__global__ __launch_bounds__(256) void k_gemm_final(const u16* __restrict__ Af,
                                                    const u16* __restrict__ P,
                                                    const float* __restrict__ bo,
                                                    const float* __restrict__ x,
                                                    float* __restrict__ out) {
    __shared__ __align__(16) char lds[24576];
    int t = threadIdx.x;
    int ntile = blockIdx.x, cot = blockIdx.y;
    int wv = t >> 6, l = t & 63;
    int lr = l & 15, lq = l >> 4;
    int wm = (wv >> 1) * 64, wn = (wv & 1) * 32;

    f32x4 acc[4][2];
#pragma unroll
    for (int i = 0; i < 4; ++i)
#pragma unroll
        for (int j = 0; j < 2; ++j) acc[i][j] = (f32x4){0.f, 0.f, 0.f, 0.f};

    auto stg = [&](int buf, int kt) {
        const char* as = (const char*)(Af + kt * 8192 + cot * 4096);
        const char* bs = (const char*)(P + kt * 524288 + ntile * 2048);
        char* al = lds + buf * 8192;
        char* bl = lds + 16384 + buf * 4096;
        gll16(as + wv * 1024 + l * 16, al + wv * 1024);
        gll16(as + 4096 + wv * 1024 + l * 16, al + 4096 + wv * 1024);
        gll16(bs + wv * 1024 + l * 16, bl + wv * 1024);
    };

    stg(0, 0);
    int cur = 0;
    for (int kt = 0; kt < 16; ++kt) {
        __syncthreads();
        if (kt + 1 < 16) stg(cur ^ 1, kt + 1);
        const u16* Ab = (const u16*)(lds + cur * 8192);
        const u16* Bb = (const u16*)(lds + 16384 + cur * 4096);
        bf16x8 af[4], bfv[2];
#pragma unroll
        for (int mf = 0; mf < 4; ++mf)
            af[mf] = *(const bf16x8*)(Ab + (wm + mf * 16 + lr) * 32 + lq * 8);
#pragma unroll
        for (int nf = 0; nf < 2; ++nf)
            bfv[nf] = *(const bf16x8*)(Bb + (wn + nf * 16 + lr) * 32 + lq * 8);
#pragma unroll
        for (int mf = 0; mf < 4; ++mf)
#pragma unroll
            for (int nf = 0; nf < 2; ++nf)
                acc[mf][nf] = __builtin_amdgcn_mfma_f32_16x16x32_bf16(
                    af[mf], bfv[nf], acc[mf][nf], 0, 0, 0);
        cur ^= 1;
    }

#pragma unroll
    for (int mf = 0; mf < 4; ++mf)
#pragma unroll
        for (int nf = 0; nf < 2; ++nf) {
            int co0 = cot * 128 + wm + mf * 16 + lq * 4;
            int n = ntile * 64 + wn + nf * 16 + lr;
            int b = n >> 12, pix = n & 4095;
#pragma unroll
            for (int r = 0; r < 4; ++r) {
                int co = co0 + r;
                int o = (b * 256 + co) * 4096 + pix;
                out[o] = acc[mf][nf][r] + bo[co] + x[o];
            }
        }
}

// -------------------- launch --------------------
extern "C" void kernel_launch(void* const* d_in, const int* in_sizes, int n_in,
                              void* d_out, int out_size, void* d_ws, size_t ws_size,
                              hipStream_t stream) {
    const float* x   = (const float*)d_in[0];
    const float* pwx = (const float*)d_in[1];
    const float* pbx = (const float*)d_in[2];
    const float* wx  = (const float*)d_in[3];
    const float* pwy = (const float*)d_in[4];
    const float* pby = (const float*)d_in[5];
    const float* wy  = (const float*)d_in[6];
    const float* wo  = (const float*)d_in[7];
    const float* bo  = (const float*)d_in[8];
    float* out = (float*)d_out;

    char* ws = (char*)d_ws;
    float* off  = (float*)(ws + 0);          //  2,359,296 B
    u16*   Apan = (u16*)  (ws + 2359296);    //  2,359,296 B
    u16*   Af   = (u16*)  (ws + 4718592);    //    262,144 B
    u16*   Aoff = (u16*)  (ws + 4980736);    //    294,912 B
    u16*   P    = (u16*)  (ws + 5275648);    // 16,777,216 B
    u16*   Bpan = (u16*)  (ws + 22052864);   // 37,748,736 B (half-batch, reused 4x)
    float* xT   = (float*)(ws + 59801600);   // 17,842,176 B (4 x 66x66x256 fp32)
    u16*   xTb  = (u16*)  (ws + 77643776);   //  8,921,088 B (4 x 66x66x256 bf16)
    // total 86,564,864 B

    k_transpose_w   <<<4608, 256, 0, stream>>>(wx, wy, Apan);
    k_transpose_wo  <<<512,  256, 0, stream>>>(wo, Af);
    k_transpose_aoff<<<576,  256, 0, stream>>>(pwx, pwy, Aoff);

    hipMemsetAsync(xT,  0, 17842176, stream);
    hipMemsetAsync(xTb, 0,  8921088, stream);
    k_transpose_x <<<dim3(64, 4),  256, 0, stream>>>(x, xT, xTb);

    k_offset_gemm <<<dim3(64, 4),  256, 0, stream>>>(Aoff, xTb, pbx, pby, off);

    for (int br = 0; br < 2; ++br)
        for (int bp = 0; bp < 2; ++bp) {
            k_sample_t    <<<dim3(16, 2, 36), 256, 0, stream>>>(xT, off, Bpan, br, bp);
            k_gemm_deform <<<dim3(128, 2),    256, 0, stream>>>(Apan, Bpan, P, br, bp);
        }

    k_gemm_final  <<<dim3(256, 2),   256, 0, stream>>>(Af, P, bo, x, out);
}

// Round 14
// 469.946 us; speedup vs baseline: 3.0431x; 1.0842x over previous
//
#include <hip/hip_runtime.h>

typedef unsigned short u16;
typedef __attribute__((ext_vector_type(8))) short bf16x8;
typedef __attribute__((ext_vector_type(4))) float f32x4;
typedef __attribute__((ext_vector_type(4))) u16 u16x4;

__device__ __forceinline__ unsigned f2bf(float f) {
    unsigned u = __float_as_uint(f);
    return (u + 0x7FFFu + ((u >> 16) & 1u)) >> 16;   // RNE, finite inputs
}

__device__ __forceinline__ void gll16(const void* g, void* l) {
    __builtin_amdgcn_global_load_lds(
        (const __attribute__((address_space(1))) char*)g,
        (__attribute__((address_space(3))) char*)l, 16, 0, 0);
}

// ---------- weight → panel transposes ----------
// Apan[br][kt72][co256][kw32], k = kt*32+kw = n9*256+ci
__global__ void k_transpose_w(const float* __restrict__ wx,
                              const float* __restrict__ wy,
                              u16* __restrict__ Apan) {
    int idx = blockIdx.x * 256 + threadIdx.x;          // < 1179648
    int br = idx / 589824, rem = idx % 589824;
    int kt = rem / 8192, r2 = rem % 8192;
    int co = r2 / 32, kw = r2 % 32;
    int k = kt * 32 + kw, n9 = k >> 8, ci = k & 255;
    const float* w = br ? wy : wx;
    Apan[idx] = (u16)f2bf(w[(co * 256 + ci) * 9 + n9]);
}

// Af[kt16][co256][kw32], k = ch in concat(Cx,Cy)
__global__ void k_transpose_wo(const float* __restrict__ wo, u16* __restrict__ Af) {
    int idx = blockIdx.x * 256 + threadIdx.x;          // < 131072
    int kt = idx / 8192, r2 = idx % 8192;
    int co = r2 / 32, kw = r2 % 32;
    Af[idx] = (u16)f2bf(wo[co * 512 + kt * 32 + kw]);
}

// Aoff[kt72][m64][kw32]: m = ch36 (0..17 branch x, 18..35 branch y), rows 36..63 zero
__global__ void k_transpose_aoff(const float* __restrict__ pwx,
                                 const float* __restrict__ pwy,
                                 u16* __restrict__ Aoff) {
    int idx = blockIdx.x * 256 + threadIdx.x;          // < 147456
    int kt = idx / 2048, r2 = idx % 2048;
    int m = r2 / 32, kw = r2 % 32;
    int k = kt * 32 + kw, n9 = k >> 8, ci = k & 255;
    float v = 0.f;
    if (m < 18)      v = pwx[(m * 256 + ci) * 9 + n9];
    else if (m < 36) v = pwy[((m - 18) * 256 + ci) * 9 + n9];
    Aoff[idx] = (u16)f2bf(v);
}

// ---------- padded NHWC transpose: xT fp32 + xTb bf16, [b][66][66][256], border pre-zeroed ----------
__global__ __launch_bounds__(256) void k_transpose_x(const float* __restrict__ x,
                                                     float* __restrict__ xT,
                                                     u16* __restrict__ xTb) {
    __shared__ float lds[256 * 65];
    int h = blockIdx.x, b = blockIdx.y;
    int t = threadIdx.x;
    int ci0 = t >> 6, w0 = t & 63;
#pragma unroll 4
    for (int it = 0; it < 64; ++it) {
        int ci = it * 4 + ci0;
        lds[ci * 65 + w0] = x[((b * 256 + ci) * 64 + h) * 64 + w0];
    }
    __syncthreads();
    float* dstrow = xT  + (size_t)b * 1115136 + ((h + 1) * 66 + 1) * 256;
    u16*   dstb   = xTb + (size_t)b * 1115136 + ((h + 1) * 66 + 1) * 256;
#pragma unroll 4
    for (int it = 0; it < 64; ++it) {
        float v = lds[t * 65 + it];
        dstrow[it * 256 + t] = v;
        dstb[it * 256 + t]   = (u16)f2bf(v);
    }
}

// ---------- offset conv as MFMA GEMM: M=64(36 real) x N=64pix x K=2304, B direct from xTb ----------
// grid (64 h, 4 b); writes off[br][b][ch18][4096] fp32 (+bias)
__global__ __launch_bounds__(256) void k_offset_gemm(const u16* __restrict__ Aoff,
                                                     const u16* __restrict__ xTb,
                                                     const float* __restrict__ pbx,
                                                     const float* __restrict__ pby,
                                                     float* __restrict__ off) {
    __shared__ __align__(16) char lds[16384];   // A 2x4KB @0, B 2x4KB @8192
    int t = threadIdx.x;
    int h = blockIdx.x, b = blockIdx.y;
    int wv = t >> 6, l = t & 63;
    int lr = l & 15, lq = l >> 4;
    int wm = (wv >> 1) * 32, wn = (wv & 1) * 32;
    const u16* xb = xTb + (size_t)b * 1115136;
    int w = t >> 2, kwq = t & 3;                 // B staging coords (pixel, 8-ch group)

    f32x4 acc[2][2];
#pragma unroll
    for (int i = 0; i < 2; ++i)
#pragma unroll
        for (int j = 0; j < 2; ++j) acc[i][j] = (f32x4){0.f, 0.f, 0.f, 0.f};

    auto stg = [&](int buf, int kt) {
        int n9 = kt >> 3, ci0 = (kt & 7) * 32;
        int ki = n9 / 3, kj = n9 % 3;
        gll16(Aoff + kt * 2048 + t * 8, lds + buf * 4096 + wv * 1024);
        const u16* bs = xb + ((h + ki) * 66 + (w + kj)) * 256 + ci0 + kwq * 8;
        gll16(bs, lds + 8192 + buf * 4096 + wv * 1024);
    };

    stg(0, 0);
    int cur = 0;
    for (int kt = 0; kt < 72; ++kt) {
        __syncthreads();
        if (kt + 1 < 72) stg(cur ^ 1, kt + 1);
        const u16* Ab = (const u16*)(lds + cur * 4096);
        const u16* Bb = (const u16*)(lds + 8192 + cur * 4096);
        bf16x8 af[2], bfv[2];
#pragma unroll
        for (int mf = 0; mf < 2; ++mf)
            af[mf] = *(const bf16x8*)(Ab + (wm + mf * 16 + lr) * 32 + lq * 8);
#pragma unroll
        for (int nf = 0; nf < 2; ++nf)
            bfv[nf] = *(const bf16x8*)(Bb + (wn + nf * 16 + lr) * 32 + lq * 8);
#pragma unroll
        for (int mf = 0; mf < 2; ++mf)
#pragma unroll
            for (int nf = 0; nf < 2; ++nf)
                acc[mf][nf] = __builtin_amdgcn_mfma_f32_16x16x32_bf16(
                    af[mf], bfv[nf], acc[mf][nf], 0, 0, 0);
        cur ^= 1;
    }

#pragma unroll
    for (int mf = 0; mf < 2; ++mf)
#pragma unroll
        for (int nf = 0; nf < 2; ++nf) {
            int m0 = wm + mf * 16 + lq * 4;
            int pix = h * 64 + wn + nf * 16 + lr;
#pragma unroll
            for (int r = 0; r < 4; ++r) {
                int m = m0 + r;
                if (m < 36) {
                    int br = m / 18, ch = m % 18;
                    float bias = br ? pby[ch] : pbx[ch];
                    off[((br * 4 + b) * 18 + ch) * 4096 + pix] = acc[mf][nf][r] + bias;
                }
            }
        }
}

// ---------- bilinear sampling from NHWC xT → bf16 K-panels ----------
// Bpan_half[kt72][n8192][kw32]; n = bloc*4096+pix (b = bp*2+bloc)
// 16 channels per thread: 16 independent float4 loads in flight
__global__ __launch_bounds__(256) void k_sample_t(const float* __restrict__ xT,
                                                  const float* __restrict__ off,
                                                  u16* __restrict__ Bpan,
                                                  int br, int bp) {
    int t = threadIdx.x;
    int h = blockIdx.x * 4 + (t >> 6);
    int w = t & 63;
    int bloc = blockIdx.y;
    int b = bp * 2 + bloc;
    int z = blockIdx.z;               // 0..143
    int n9 = z % 9, c16 = z / 9;      // 16-channel chunk
    int pix = h * 64 + w;

    float offx = off[((br * 4 + b) * 18 + n9) * 4096 + pix];
    float offy = off[((br * 4 + b) * 18 + n9 + 9) * 4096 + pix];
    int ki = n9 / 3, kj = n9 % 3;
    float px = offx + (float)(ki - 1) + (float)(h + 1);
    float py = offy + (float)(kj - 1) + (float)(w + 1);
    float fx = floorf(px), fy = floorf(py);
    int ltx = min(max((int)fx, 0), 65);
    int lty = min(max((int)fy, 0), 65);
    int rbx = min(max((int)fx + 1, 0), 65);
    int rby = min(max((int)fy + 1, 0), 65);
    float pxc = fminf(fmaxf(px, 0.f), 65.f);
    float pyc = fminf(fmaxf(py, 0.f), 65.f);
    float axl = 1.f + ((float)ltx - pxc);
    float axr = 1.f - ((float)rbx - pxc);
    float ayl = 1.f + ((float)lty - pyc);
    float ayr = 1.f - ((float)rby - pyc);
    float glt = axl * ayl, grb = axr * ayr, glb = axl * ayr, grt = axr * ayl;

    const float* base = xT + (size_t)b * 1115136 + c16 * 16;   // 66*66*256
    const float4* p00 = (const float4*)(base + (ltx * 66 + lty) * 256);
    const float4* p11 = (const float4*)(base + (rbx * 66 + rby) * 256);
    const float4* p01 = (const float4*)(base + (ltx * 66 + rby) * 256);
    const float4* p10 = (const float4*)(base + (rbx * 66 + lty) * 256);

    float4 va[4], vb[4], vc[4], vd[4];
#pragma unroll
    for (int q = 0; q < 4; ++q) {
        va[q] = p00[q]; vb[q] = p11[q]; vc[q] = p01[q]; vd[q] = p10[q];
    }
    unsigned r[8];
#pragma unroll
    for (int q = 0; q < 4; ++q) {
        float f0 = glt * va[q].x + grb * vb[q].x + glb * vc[q].x + grt * vd[q].x;
        float f1 = glt * va[q].y + grb * vb[q].y + glb * vc[q].y + grt * vd[q].y;
        float f2 = glt * va[q].z + grb * vb[q].z + glb * vc[q].z + grt * vd[q].z;
        float f3 = glt * va[q].w + grb * vb[q].w + glb * vc[q].w + grt * vd[q].w;
        r[q * 2]     = f2bf(f0) | (f2bf(f1) << 16);
        r[q * 2 + 1] = f2bf(f2) | (f2bf(f3) << 16);
    }
    int ci = c16 * 16;
    int kt = n9 * 8 + (ci >> 5);
    int kw = ci & 31;                 // 0 or 16
    uint4* dst = (uint4*)(Bpan + (kt * 8192 + bloc * 4096 + pix) * 32 + kw);
    dst[0] = make_uint4(r[0], r[1], r[2], r[3]);
    dst[1] = make_uint4(r[4], r[5], r[6], r[7]);
}

// ---------- deformable-conv GEMM: tile 64co x 64n, K=2304, N=8192 per launch ----------
// grid (128 ntiles, 4 cot) = 512 blocks (2/CU); writes P[kt16][n16384][32] at n-offset bp*8192
__global__ __launch_bounds__(256) void k_gemm_deform(const u16* __restrict__ Apan,
                                                     const u16* __restrict__ Bpan,
                                                     u16* __restrict__ P,
                                                     int br, int bp) {
    __shared__ __align__(16) char lds[16384];   // A 2x4KB @0, B 2x4KB @8192; epi E[64][72]
    int t = threadIdx.x;
    int ntile = blockIdx.x, cot = blockIdx.y;
    int wv = t >> 6, l = t & 63;
    int lr = l & 15, lq = l >> 4;
    int wm = (wv >> 1) * 32, wn = (wv & 1) * 32;

    f32x4 acc[2][2];
#pragma unroll
    for (int i = 0; i < 2; ++i)
#pragma unroll
        for (int j = 0; j < 2; ++j) acc[i][j] = (f32x4){0.f, 0.f, 0.f, 0.f};

    auto stg = [&](int buf, int kt) {
        const char* as = (const char*)(Apan + (br * 72 + kt) * 8192 + cot * 2048);
        const char* bs = (const char*)(Bpan + kt * 262144 + ntile * 2048);
        gll16(as + t * 16, lds + buf * 4096 + wv * 1024);
        gll16(bs + t * 16, lds + 8192 + buf * 4096 + wv * 1024);
    };

    stg(0, 0);
    int cur = 0;
    for (int kt = 0; kt < 72; ++kt) {
        __syncthreads();
        if (kt + 1 < 72) stg(cur ^ 1, kt + 1);
        const u16* Ab = (const u16*)(lds + cur * 4096);
        const u16* Bb = (const u16*)(lds + 8192 + cur * 4096);
        bf16x8 af[2], bfv[2];
#pragma unroll
        for (int mf = 0; mf < 2; ++mf)
            af[mf] = *(const bf16x8*)(Ab + (wm + mf * 16 + lr) * 32 + lq * 8);
#pragma unroll
        for (int nf = 0; nf < 2; ++nf)
            bfv[nf] = *(const bf16x8*)(Bb + (wn + nf * 16 + lr) * 32 + lq * 8);
#pragma unroll
        for (int mf = 0; mf < 2; ++mf)
#pragma unroll
            for (int nf = 0; nf < 2; ++nf)
                acc[mf][nf] = __builtin_amdgcn_mfma_f32_16x16x32_bf16(
                    af[mf], bfv[nf], acc[mf][nf], 0, 0, 0);
        cur ^= 1;
    }

    __syncthreads();
    u16 (*E)[72] = (u16(*)[72])lds;             // [n64][m64+pad]
#pragma unroll
    for (int mf = 0; mf < 2; ++mf)
#pragma unroll
        for (int nf = 0; nf < 2; ++nf) {
            int n = wn + nf * 16 + lr;
            int m0 = wm + mf * 16 + lq * 4;
            u16x4 pk;
#pragma unroll
            for (int r = 0; r < 4; ++r)
                pk[r] = (u16)f2bf(acc[mf][nf][r]);
            *(u16x4*)&E[n][m0] = pk;
        }
    __syncthreads();
    int ktl  = t >> 7;                // 0..1
    int half = t & 1;                 // 16-u16 half of the 32-wide row
    int nl   = (t >> 1) & 63;
    int ktbase = br * 8 + cot * 2;
    const uint4* src = (const uint4*)&E[nl][ktl * 32 + half * 16];
    uint4* dst = (uint4*)(P + ((ktbase + ktl) * 16384 + bp * 8192 + ntile * 64 + nl) * 32 + half * 16);
    dst[0] = src[0];
    dst[1] = src[1];
}

// ---------- 1x1 conv GEMM: tile 128co x 64n, K=512 + bias + residual ----------
__global__ __launch_bounds__(256) void k_gemm_final(const u16* __restrict__ Af,
                                                    const u16* __restrict__ P,
                                                    const float* __restrict__ bo,
                                                    const float* __restrict__ x,
                                                    float* __restrict__ out) {
    __shared__ __align__(16) char lds[24576];
    int t = threadIdx.x;
    int ntile = blockIdx.x, cot = blockIdx.y;
    int wv = t >> 6, l = t & 63;
    int lr = l & 15, lq = l >> 4;
    int wm = (wv >> 1) * 64, wn = (wv & 1) * 32;

    f32x4 acc[4][2];
#pragma unroll
    for (int i = 0; i < 4; ++i)
#pragma unroll
        for (int j = 0; j < 2; ++j) acc[i][j] = (f32x4){0.f, 0.f, 0.f, 0.f};

    auto stg = [&](int buf, int kt) {
        const char* as = (const char*)(Af + kt * 8192 + cot * 4096);
        const char* bs = (const char*)(P + kt * 524288 + ntile * 2048);
        char* al = lds + buf * 8192;
        char* bl = lds + 16384 + buf * 4096;
        gll16(as + wv * 1024 + l * 16, al + wv * 1024);
        gll16(as + 4096 + wv * 1024 + l * 16, al + 4096 + wv * 1024);
        gll16(bs + wv * 1024 + l * 16, bl + wv * 1024);
    };

    stg(0, 0);
    int cur = 0;
    for (int kt = 0; kt < 16; ++kt) {
        __syncthreads();
        if (kt + 1 < 16) stg(cur ^ 1, kt + 1);
        const u16* Ab = (const u16*)(lds + cur * 8192);
        const u16* Bb = (const u16*)(lds + 16384 + cur * 4096);
        bf16x8 af[4], bfv[2];
#pragma unroll
        for (int mf = 0; mf < 4; ++mf)
            af[mf] = *(const bf16x8*)(Ab + (wm + mf * 16 + lr) * 32 + lq * 8);
#pragma unroll
        for (int nf = 0; nf < 2; ++nf)
            bfv[nf] = *(const bf16x8*)(Bb + (wn + nf * 16 + lr) * 32 + lq * 8);
#pragma unroll
        for (int mf = 0; mf < 4; ++mf)
#pragma unroll
            for (int nf = 0; nf < 2; ++nf)
                acc[mf][nf] = __builtin_amdgcn_mfma_f32_16x16x32_bf16(
                    af[mf], bfv[nf], acc[mf][nf], 0, 0, 0);
        cur ^= 1;
    }

#pragma unroll
    for (int mf = 0; mf < 4; ++mf)
#pragma unroll
        for (int nf = 0; nf < 2; ++nf) {
            int co0 = cot * 128 + wm + mf * 16 + lq * 4;
            int n = ntile * 64 + wn + nf * 16 + lr;
            int b = n >> 12, pix = n & 4095;
#pragma unroll
            for (int r = 0; r < 4; ++r) {
                int co = co0 + r;
                int o = (b * 256 + co) * 4096 + pix;
                out[o] = acc[mf][nf][r] + bo[co] + x[o];
            }
        }
}

// -------------------- launch --------------------
extern "C" void kernel_launch(void* const* d_in, const int* in_sizes, int n_in,
                              void* d_out, int out_size, void* d_ws, size_t ws_size,
                              hipStream_t stream) {
    const float* x   = (const float*)d_in[0];
    const float* pwx = (const float*)d_in[1];
    const float* pbx = (const float*)d_in[2];
    const float* wx  = (const float*)d_in[3];
    const float* pwy = (const float*)d_in[4];
    const float* pby = (const float*)d_in[5];
    const float* wy  = (const float*)d_in[6];
    const float* wo  = (const float*)d_in[7];
    const float* bo  = (const float*)d_in[8];
    float* out = (float*)d_out;

    char* ws = (char*)d_ws;
    float* off  = (float*)(ws + 0);          //  2,359,296 B
    u16*   Apan = (u16*)  (ws + 2359296);    //  2,359,296 B
    u16*   Af   = (u16*)  (ws + 4718592);    //    262,144 B
    u16*   Aoff = (u16*)  (ws + 4980736);    //    294,912 B
    u16*   P    = (u16*)  (ws + 5275648);    // 16,777,216 B
    u16*   Bpan = (u16*)  (ws + 22052864);   // 37,748,736 B (half-batch, reused 4x)
    float* xT   = (float*)(ws + 59801600);   // 17,842,176 B (4 x 66x66x256 fp32)
    u16*   xTb  = (u16*)  (ws + 77643776);   //  8,921,088 B (4 x 66x66x256 bf16)
    // total 86,564,864 B

    k_transpose_w   <<<4608, 256, 0, stream>>>(wx, wy, Apan);
    k_transpose_wo  <<<512,  256, 0, stream>>>(wo, Af);
    k_transpose_aoff<<<576,  256, 0, stream>>>(pwx, pwy, Aoff);

    hipMemsetAsync(xT,  0, 17842176, stream);
    hipMemsetAsync(xTb, 0,  8921088, stream);
    k_transpose_x <<<dim3(64, 4),  256, 0, stream>>>(x, xT, xTb);

    k_offset_gemm <<<dim3(64, 4),  256, 0, stream>>>(Aoff, xTb, pbx, pby, off);

    for (int br = 0; br < 2; ++br)
        for (int bp = 0; bp < 2; ++bp) {
            k_sample_t    <<<dim3(16, 2, 144), 256, 0, stream>>>(xT, off, Bpan, br, bp);
            k_gemm_deform <<<dim3(128, 4),     256, 0, stream>>>(Apan, Bpan, P, br, bp);
        }

    k_gemm_final  <<<dim3(256, 2),   256, 0, stream>>>(Af, P, bo, x, out);
}